// Round 13
// baseline (77.633 us; speedup 1.0000x reference)
//
#include <hip/hip_runtime.h>
#include <hip/hip_bf16.h>

// Problem constants: N=4096, D=512, H=256, O=256, M=8, K=2, F=512, C=2
#define N_TOK 4096
#define D_IN  512
#define H_DIM 256
#define O_DIM 256
#define M_EXP 8
#define F_DIM 512
#define NGRP  16          // 2 modalities x 8 experts

typedef __attribute__((ext_vector_type(8))) short bf16x8;   // 8 bf16 = 4 VGPRs
typedef __attribute__((ext_vector_type(4))) float f32x4;    // MFMA C/D frag

#define VMCNT(n)  asm volatile("s_waitcnt vmcnt(" #n ")" ::: "memory")
#define LGKMCNT0  asm volatile("s_waitcnt lgkmcnt(0)" ::: "memory")
#define BARRIER() __builtin_amdgcn_s_barrier()

// RNE f32 -> bf16 bits
__device__ __forceinline__ unsigned short f2bf(float f) {
    unsigned int u = __float_as_uint(f);
    u = (u + 0x7FFFu + ((u >> 16) & 1u)) >> 16;
    return (unsigned short)u;
}
__device__ __forceinline__ float b2f(unsigned short u) {
    return __uint_as_float((unsigned int)u << 16);
}

// async global->LDS, 16B per lane; LDS dest wave-uniform base + lane*16
__device__ __forceinline__ void gload_lds16(const void* g, void* l) {
    __builtin_amdgcn_global_load_lds(
        (const __attribute__((address_space(1))) unsigned int*)g,
        (__attribute__((address_space(3))) unsigned int*)l, 16, 0, 0);
}

// Swizzled LDS byte offset for [R][32 bf16] tiles (64B rows, 4x16B slots).
__device__ __forceinline__ int sw64(int row, int lslot) {
    return row * 64 + ((lslot ^ ((row >> 1) & 3)) << 4);
}
// 512B rows (32x16B slots): slot ^= row&7.
__device__ __forceinline__ int swHs(int row, int lslot) {
    return row * 512 + ((lslot ^ (row & 7)) << 4);
}
// 1024B rows (64x16B slots): slot ^= row&7.
__device__ __forceinline__ int swAs(int row, int lslot) {
    return row * 1024 + ((lslot ^ (row & 7)) << 4);
}

// ---------------------------------------------------------------------------
// Kernel 1 (merged): weight transposes + WfT fold + out init + sum_out zero +
// gating. Gating: 512 blocks, 16 tokens each (4/wave, Wg reused in regs;
// lanes 0-3 process one token each after the butterfly). Reduce tree and
// per-lane d-mapping identical to earlier rounds -> logits bit-identical.
// ---------------------------------------------------------------------------
__global__ __launch_bounds__(256) void prep_gate_kernel(
    const float* __restrict__ Xb, const float* __restrict__ Xc,
    const float* __restrict__ Wg, const float* __restrict__ bg,
    const float* __restrict__ W1, const float* __restrict__ W2,
    const float* __restrict__ Wf, const float* __restrict__ bc,
    unsigned short* __restrict__ W1T, unsigned short* __restrict__ W2T,
    unsigned short* __restrict__ WfT, unsigned short* __restrict__ Xbf,
    float* __restrict__ cfd, int* __restrict__ eidx,
    float* __restrict__ gpart, float* __restrict__ cpart,
    float* __restrict__ sum_out, float* __restrict__ out)
{
    __shared__ float tile[32][33];
    __shared__ float s_g[M_EXP];
    __shared__ float s_c[M_EXP];
    const int bx = blockIdx.x;
    const int tr = threadIdx.x >> 3, q = threadIdx.x & 7;

    if (bx < 1024) {            // W1 [8][512][256] -> W1T [8][256][512]
        const int e = bx >> 7, tidx = bx & 127;
        const int r0 = (tidx >> 3) * 32, c0 = (tidx & 7) * 32;
        const float* s = W1 + (size_t)e * 512 * 256;
        unsigned short* d = W1T + (size_t)e * 512 * 256;
        *(float4*)&tile[tr][q * 4] = *(const float4*)&s[(size_t)(r0 + tr) * 256 + c0 + q * 4];
        __syncthreads();
        ushort4 o;
        o.x = f2bf(tile[q*4+0][tr]); o.y = f2bf(tile[q*4+1][tr]);
        o.z = f2bf(tile[q*4+2][tr]); o.w = f2bf(tile[q*4+3][tr]);
        *(ushort4*)&d[(size_t)(c0 + tr) * 512 + r0 + q * 4] = o;
    } else if (bx < 1536) {     // W2 [8][256][256] -> W2T [8][256][256]
        const int idx = bx - 1024;
        const int e = idx >> 6, tidx = idx & 63;
        const int r0 = (tidx >> 3) * 32, c0 = (tidx & 7) * 32;
        const float* s = W2 + (size_t)e * 256 * 256;
        unsigned short* d = W2T + (size_t)e * 256 * 256;
        *(float4*)&tile[tr][q * 4] = *(const float4*)&s[(size_t)(r0 + tr) * 256 + c0 + q * 4];
        __syncthreads();
        ushort4 o;
        o.x = f2bf(tile[q*4+0][tr]); o.y = f2bf(tile[q*4+1][tr]);
        o.z = f2bf(tile[q*4+2][tr]); o.w = f2bf(tile[q*4+3][tr]);
        *(ushort4*)&d[(size_t)(c0 + tr) * 256 + r0 + q * 4] = o;
    } else if (bx < 1792) {     // WfT_eff[f][j] = Wf[j][f] + (j>=256 ? Wf[j+256][f] : 0)
        const int idx = bx - 1536;
        const int j0 = (idx >> 4) * 32, f0 = (idx & 15) * 32;
        float4 v = *(const float4*)&Wf[(size_t)(j0 + tr) * F_DIM + f0 + q * 4];
        if (j0 >= 256) {
            const float4 v2 = *(const float4*)&Wf[(size_t)(j0 + tr + 256) * F_DIM + f0 + q * 4];
            v.x += v2.x; v.y += v2.y; v.z += v2.z; v.w += v2.w;
        }
        *(float4*)&tile[tr][q * 4] = v;
        __syncthreads();
        ushort4 o;
        o.x = f2bf(tile[q*4+0][tr]); o.y = f2bf(tile[q*4+1][tr]);
        o.z = f2bf(tile[q*4+2][tr]); o.w = f2bf(tile[q*4+3][tr]);
        *(ushort4*)&WfT[(size_t)(f0 + tr) * 512 + j0 + q * 4] = o;
    } else if (bx < 1824) {     // out init
        const int i = (bx - 1792) * 256 + threadIdx.x;
        out[i] = bc[i & 1];
    } else if (bx < 1825) {     // zero sum_out
#pragma unroll
        for (int k = 0; k < 8; ++k) sum_out[threadIdx.x * 8 + k] = 0.f;
    } else {                    // ---------------- gating: 16 tokens/block ----------------
        const int idx = bx - 1825;          // [0, 512)
        const int mod = idx >> 8;
        const int b = idx & 255;
        const float* X = mod ? Xc : Xb;
        const int wave = threadIdx.x >> 6;
        const int lane = threadIdx.x & 63;
        const int n0 = b * 16 + wave * 4;   // 4 tokens per wave

        if (threadIdx.x < M_EXP) { s_g[threadIdx.x] = 0.f; s_c[threadIdx.x] = 0.f; }
        __syncthreads();

        float acc[4][M_EXP];
#pragma unroll
        for (int j = 0; j < 4; ++j)
#pragma unroll
            for (int m = 0; m < M_EXP; ++m) acc[j][m] = 0.f;

#pragma unroll
        for (int k = 0; k < 8; ++k) {
            const int d = lane + 64 * k;
            float wr[M_EXP];
#pragma unroll
            for (int m = 0; m < M_EXP; ++m) wr[m] = Wg[d * M_EXP + m];
#pragma unroll
            for (int j = 0; j < 4; ++j) {
                const float xv = X[(size_t)(n0 + j) * D_IN + d];
                Xbf[(size_t)mod * N_TOK * D_IN + (size_t)(n0 + j) * D_IN + d] = f2bf(xv);
#pragma unroll
                for (int m = 0; m < M_EXP; ++m) acc[j][m] += xv * wr[m];
            }
        }
#pragma unroll
        for (int off = 1; off < 64; off <<= 1) {
#pragma unroll
            for (int j = 0; j < 4; ++j)
#pragma unroll
                for (int m = 0; m < M_EXP; ++m) acc[j][m] += __shfl_xor(acc[j][m], off, 64);
        }

        // lanes 0-3: each processes token j=lane (all lanes have full sums)
        if (lane < 4) {
            const int j = lane;
            const int n = n0 + j;
            float g[M_EXP];
            float mx = -1e30f;
#pragma unroll
            for (int m = 0; m < M_EXP; ++m) { g[m] = acc[j][m] + bg[m]; mx = fmaxf(mx, g[m]); }
            float es = 0.f;
#pragma unroll
            for (int m = 0; m < M_EXP; ++m) { g[m] = expf(g[m] - mx); es += g[m]; }
            const float inv = 1.f / es;
#pragma unroll
            for (int m = 0; m < M_EXP; ++m) g[m] *= inv;

            int i0 = 0; float v0 = g[0];
#pragma unroll
            for (int m = 1; m < M_EXP; ++m) if (g[m] > v0) { v0 = g[m]; i0 = m; }
            int i1 = -1; float v1 = -1e30f;
#pragma unroll
            for (int m = 0; m < M_EXP; ++m) if (m != i0 && g[m] > v1) { v1 = g[m]; i1 = m; }

            const float wn = 1.f / (v0 + v1);
#pragma unroll
            for (int m = 0; m < M_EXP; ++m) {
                const float cv = (m == i0) ? v0 * wn : (m == i1) ? v1 * wn : 0.f;
                cfd[(size_t)(mod * M_EXP + m) * N_TOK + n] = cv;
            }
            eidx[(mod * N_TOK + n) * 2 + 0] = i0;
            eidx[(mod * N_TOK + n) * 2 + 1] = i1;
#pragma unroll
            for (int m = 0; m < M_EXP; ++m) atomicAdd(&s_g[m], g[m]);
            atomicAdd(&s_c[i0], 1.f);
            atomicAdd(&s_c[i1], 1.f);
        }
        __syncthreads();
        if (threadIdx.x < M_EXP) {
            gpart[idx * M_EXP + threadIdx.x] = s_g[threadIdx.x];   // [512][8]
            cpart[idx * M_EXP + threadIdx.x] = s_c[threadIdx.x];
        }
    }
}

// ---------------------------------------------------------------------------
// Compaction: one block per group. Prefix-sum over cfd[g][*] -> token-ordered
// list/cwgt, inverse map invslot[g][n], count, pad to 32 multiple.
// ---------------------------------------------------------------------------
__global__ __launch_bounds__(256) void compact_kernel(
    const float* __restrict__ cfd, int* __restrict__ cnti,
    int* __restrict__ list, float* __restrict__ cwgt, int* __restrict__ invslot)
{
    __shared__ int scnt[256];
    const int g = blockIdx.x;
    const int t = threadIdx.x;
    float v[16];
    int cnt = 0;
#pragma unroll
    for (int k = 0; k < 16; ++k) {
        v[k] = cfd[(size_t)g * N_TOK + t * 16 + k];
        cnt += (v[k] > 0.f) ? 1 : 0;
    }
    scnt[t] = cnt;
    __syncthreads();
    for (int off = 1; off < 256; off <<= 1) {
        const int y = (t >= off) ? scnt[t - off] : 0;
        __syncthreads();
        scnt[t] += y;
        __syncthreads();
    }
    const int total = scnt[255];
    int pos = scnt[t] - cnt;                 // exclusive prefix
#pragma unroll
    for (int k = 0; k < 16; ++k) {
        if (v[k] > 0.f) {
            const int n = t * 16 + k;
            list[g * N_TOK + pos] = n;
            cwgt[g * N_TOK + pos] = v[k];
            invslot[g * N_TOK + n] = pos;
            ++pos;
        }
    }
    const int padded = (total + 31) & ~31;
    for (int i = total + t; i < padded; i += 256) {
        list[g * N_TOK + i] = 0;
        cwgt[g * N_TOK + i] = 0.f;
    }
    if (t == 0) cnti[g] = total;
}

// ---------------------------------------------------------------------------
// Fused gathered expert kernel (unchanged from round 12, the 21µs winner).
// ---------------------------------------------------------------------------
__global__ __launch_bounds__(256, 4) void hy_gemm_kernel(
    const unsigned short* __restrict__ Xbf,    // [2][4096][512] bf16
    const unsigned short* __restrict__ W1T,    // [8][256][512] bf16
    const unsigned short* __restrict__ W2T,    // [8][256][256] bf16
    const float* __restrict__ b1, const float* __restrict__ b2,
    const int* __restrict__ cnti, const int* __restrict__ list,
    const float* __restrict__ cwgt,
    unsigned short* __restrict__ Ybuf,         // [16][4096][256] bf16 (weighted)
    float* __restrict__ sum_out)
{
    __shared__ __align__(16) char lds[36864];

    const int bid = blockIdx.x;
    const int xcd = bid & 7, r = bid >> 3;
    const int g  = xcd * 2 + (r & 1);
    const int rt = r >> 1;
    const int cnt = cnti[g];
    if (rt * 32 >= cnt) return;
    const int e = g & 7, mod = g >> 3;
    const int r0 = rt * 32;

    const int t = threadIdx.x;
    const int w = t >> 6, l = t & 63;
    const int lr = l & 15, lk = l >> 4;
    const int wcol = w * 64;

    const unsigned short* w1p = W1T + (size_t)e * H_DIM * D_IN;
    const unsigned short* w2p = W2T + (size_t)e * O_DIM * H_DIM;

    float bv1[4], bv2[4];
#pragma unroll
    for (int nj = 0; nj < 4; ++nj) {
        bv1[nj] = b1[e * 256 + wcol + nj * 16 + lr];
        bv2[nj] = b2[e * 256 + wcol + nj * 16 + lr];
    }

    const unsigned short* aptr = nullptr;
    if (w < 2) {
        const int arow = w * 16 + (l >> 2);
        const int ls = (l & 3) ^ ((arow >> 1) & 3);
        const int n = list[g * N_TOK + r0 + arow];
        aptr = Xbf + (size_t)mod * N_TOK * D_IN + (size_t)n * 512 + ls * 8;
    }
    const int brl = l >> 2;
    const int bp = l & 3;

    f32x4 acc[2][4];
#pragma unroll
    for (int mi = 0; mi < 2; ++mi)
#pragma unroll
        for (int nj = 0; nj < 4; ++nj) { f32x4 z = {0.f,0.f,0.f,0.f}; acc[mi][nj] = z; }

    for (int kc = 0; kc < 16; ++kc) {
        if (w < 2) gload_lds16(aptr + kc * 32, lds + w * 1024);
#pragma unroll
        for (int s = 0; s < 4; ++s) {
            const int row = w * 64 + s * 16 + brl;
            const int ls = bp ^ ((row >> 1) & 3);
            gload_lds16(w1p + (size_t)row * 512 + kc * 32 + ls * 8,
                        lds + 2048 + w * 4096 + s * 1024);
        }
        __syncthreads();
        bf16x8 a[2], b[4];
#pragma unroll
        for (int mi = 0; mi < 2; ++mi)
            a[mi] = *(const bf16x8*)(lds + sw64(mi * 16 + lr, lk));
#pragma unroll
        for (int nj = 0; nj < 4; ++nj)
            b[nj] = *(const bf16x8*)(lds + 2048 + sw64(wcol + nj * 16 + lr, lk));
#pragma unroll
        for (int mi = 0; mi < 2; ++mi)
#pragma unroll
            for (int nj = 0; nj < 4; ++nj)
                acc[mi][nj] = __builtin_amdgcn_mfma_f32_16x16x32_bf16(a[mi], b[nj], acc[mi][nj], 0, 0, 0);
        __syncthreads();
    }

#pragma unroll
    for (int mi = 0; mi < 2; ++mi)
#pragma unroll
        for (int nj = 0; nj < 4; ++nj) {
            const int col = wcol + nj * 16 + lr;
            const int cslot = col >> 3;
            const int cbyte = (col & 7) * 2;
#pragma unroll
            for (int j = 0; j < 4; ++j) {
                const int row = mi * 16 + lk * 4 + j;
                *(unsigned short*)(lds + 18432 + row * 512 + ((cslot ^ (row & 7)) << 4) + cbyte) =
                    f2bf(fmaxf(acc[mi][nj][j] + bv1[nj], 0.f));
            }
        }
#pragma unroll
    for (int mi = 0; mi < 2; ++mi)
#pragma unroll
        for (int nj = 0; nj < 4; ++nj) { f32x4 z = {0.f,0.f,0.f,0.f}; acc[mi][nj] = z; }

    for (int kc = 0; kc < 8; ++kc) {
#pragma unroll
        for (int s = 0; s < 4; ++s) {
            const int row = w * 64 + s * 16 + brl;
            const int ls = bp ^ ((row >> 1) & 3);
            gload_lds16(w2p + (size_t)row * 256 + kc * 32 + ls * 8,
                        lds + 2048 + w * 4096 + s * 1024);
        }
        __syncthreads();
        bf16x8 a[2], b[4];
#pragma unroll
        for (int mi = 0; mi < 2; ++mi)
            a[mi] = *(const bf16x8*)(lds + 18432 + swHs(mi * 16 + lr, kc * 4 + lk));
#pragma unroll
        for (int nj = 0; nj < 4; ++nj)
            b[nj] = *(const bf16x8*)(lds + 2048 + sw64(wcol + nj * 16 + lr, lk));
#pragma unroll
        for (int mi = 0; mi < 2; ++mi)
#pragma unroll
            for (int nj = 0; nj < 4; ++nj)
                acc[mi][nj] = __builtin_amdgcn_mfma_f32_16x16x32_bf16(a[mi], b[nj], acc[mi][nj], 0, 0, 0);
        __syncthreads();
    }

    float sacc[4] = {0.f, 0.f, 0.f, 0.f};
#pragma unroll
    for (int mi = 0; mi < 2; ++mi)
#pragma unroll
        for (int j2 = 0; j2 < 4; ++j2) {
            const int row = mi * 16 + lk * 4 + j2;
            const float wv = cwgt[g * N_TOK + r0 + row];
            const bool valid = wv > 0.f;
#pragma unroll
            for (int nj = 0; nj < 4; ++nj) {
                const float v = acc[mi][nj][j2] + bv2[nj];
                if (valid) sacc[nj] += v;
                const int col = wcol + nj * 16 + lr;
                *(unsigned short*)(lds + row * 512 + col * 2) = f2bf(wv * v);
            }
        }
    __syncthreads();
#pragma unroll
    for (int q2 = 0; q2 < 4; ++q2) {
        const int u = q2 * 256 + t;
        const int row = u >> 5, cs = u & 31;
        *(bf16x8*)(Ybuf + (((size_t)g * N_TOK + r0 + row) * 256 + cs * 8)) =
            *(const bf16x8*)(lds + u * 16);
    }
#pragma unroll
    for (int nj = 0; nj < 4; ++nj) {
        sacc[nj] += __shfl_xor(sacc[nj], 16, 64);
        sacc[nj] += __shfl_xor(sacc[nj], 32, 64);
    }
    if (lk == 0) {
        const float modw = mod ? 2.f : 1.f;
#pragma unroll
        for (int nj = 0; nj < 4; ++nj)
            atomicAdd(&sum_out[e * O_DIM + wcol + nj * 16 + lr], sacc[nj] * modw);
    }
}

// ---------------------------------------------------------------------------
// Fusion + classifier (x<128, 4 col-quarters) + losses (x==128,y==0).
// BN=128 per block -> ~514 blocks (2/CU). K-loop is BARRIER-FREE: each wave
// stages and reads only its own B rows; triple-buffered Ws + counted VMCNT.
// One barrier only after the cross-wave A-stage.
// ---------------------------------------------------------------------------
__global__ __launch_bounds__(256, 2) void fuse_cls_loss_kernel(
    const unsigned short* __restrict__ Ybuf,
    const int* __restrict__ eidx, const int* __restrict__ invslot,
    const unsigned short* __restrict__ WfT, const float* __restrict__ bf,
    const float* __restrict__ Wc,
    const float* __restrict__ gpart, const float* __restrict__ cpart,
    const float* __restrict__ sum_out, float* __restrict__ out)
{
    __shared__ __align__(16) char As[32 * 1024];   // 32KB
    __shared__ __align__(16) char Ws[3][8192];     // 24KB (triple buffer)
    __shared__ float avg[M_EXP][O_DIM];
    __shared__ float partl[256];
    __shared__ float rho_s[M_EXP], rhohat_s[M_EXP];
    __shared__ float simv[28], prs[28];

    const int t = threadIdx.x;

    if (blockIdx.x == 128) {                       // ---------- loss ----------
        if (blockIdx.y != 0) return;
        const int e = t & 7, grp = t >> 3;         // gpart is [512][8] now
        float sg = 0.f, sc = 0.f;
        for (int b2 = grp * 16; b2 < grp * 16 + 16; ++b2) {
            const float wgt = (b2 < 256) ? 1.f : 2.f;
            sg += wgt * gpart[b2 * 8 + e];
            sc += wgt * cpart[b2 * 8 + e];
        }
        partl[t] = sg; __syncthreads();
        if (t < 8) { float s = 0.f; for (int g2 = 0; g2 < 32; ++g2) s += partl[t + 8 * g2]; rhohat_s[t] = s; }
        __syncthreads();
        partl[t] = sc; __syncthreads();
        if (t < 8) { float s = 0.f; for (int g2 = 0; g2 < 32; ++g2) s += partl[t + 8 * g2]; rho_s[t] = s; }
        __syncthreads();
        for (int idx = t; idx < M_EXP * O_DIM; idx += 256)
            avg[idx >> 8][idx & 255] = sum_out[idx] / fmaxf(rho_s[idx >> 8], 1.f);
        __syncthreads();
        if (t < 28) {
            int a = 0, p = t;
            while (p >= 7 - a) { p -= 7 - a; ++a; }
            const int b = a + 1 + p;
            float d2 = 0.f;
            for (int o = 0; o < O_DIM; ++o) {
                const float df = avg[a][o] - avg[b][o];
                d2 = fmaf(df, df, d2);
            }
            const bool pr = (rho_s[a] > 0.f) && (rho_s[b] > 0.f);
            simv[t] = pr ? expf(-0.5f * d2) : 0.f;
            prs[t]  = pr ? 1.f : 0.f;
        }
        __syncthreads();
        if (t == 0) {
            float s = 0.f, np = 0.f;
            for (int p = 0; p < 28; ++p) { s += simv[p]; np += prs[p]; }
            out[N_TOK * 2 + 0] = -s / fmaxf(np, 1.f);
            float eq = 0.f;
            for (int m = 0; m < M_EXP; ++m) eq = fmaf(rho_s[m], rhohat_s[m], eq);
            out[N_TOK * 2 + 1] = eq / (float)M_EXP;
        }
        return;
    }

    // ---------- fusion + classifier (BN=128, barrier-free K-loop) ----------
    const int w = t >> 6, l = t & 63;
    const int lr = l & 15, lk = l >> 4;
    const int base = blockIdx.x * 32;
    const int quarter = blockIdx.y;                // [0,4): 128 f-cols each
    const int colbase = quarter * 128 + w * 32;    // wave owns 32 cols
    const unsigned short* wfp = WfT + (size_t)quarter * 128 * 512;

    const int wrl = l >> 2;
    const int wp = l & 3;
    // per-wave self-staging: wave w stages B rows [w*32, w*32+32)
    auto stage_w = [&](int kc) {
        const int buf = kc % 3;
#pragma unroll
        for (int s2 = 0; s2 < 2; ++s2) {
            const int row = w * 32 + s2 * 16 + wrl;
            const int lslot = wp ^ ((row >> 1) & 3);
            gload_lds16(wfp + (size_t)row * 512 + kc * 32 + lslot * 8,
                        &Ws[buf][w * 2048 + s2 * 1024]);
        }
    };

    stage_w(0);
    stage_w(1);

    {   // A stage: combined[32][512] = gathered sums of 2 weighted Y rows
        const int r = t >> 3;
        const int c0 = (t & 7) * 64;
        const int n = base + r;
        const int mod = c0 >> 8;
        const int cc = c0 & 255;
        const int i0 = eidx[(mod * N_TOK + n) * 2 + 0];
        const int i1 = eidx[(mod * N_TOK + n) * 2 + 1];
        const int g0 = mod * M_EXP + i0, g1 = mod * M_EXP + i1;
        const int s0 = invslot[g0 * N_TOK + n];
        const int s1 = invslot[g1 * N_TOK + n];
        const unsigned short* y0 = Ybuf + ((size_t)g0 * N_TOK + s0) * 256 + cc;
        const unsigned short* y1 = Ybuf + ((size_t)g1 * N_TOK + s1) * 256 + cc;
#pragma unroll
        for (int q = 0; q < 8; ++q) {
            const bf16x8 a0 = *(const bf16x8*)(y0 + q * 8);
            const bf16x8 a1 = *(const bf16x8*)(y1 + q * 8);
            bf16x8 p;
#pragma unroll
            for (int j = 0; j < 8; ++j)
                p[j] = (short)f2bf(b2f((unsigned short)a0[j]) + b2f((unsigned short)a1[j]));
            *(bf16x8*)&As[swAs(r, (t & 7) * 8 + q)] = p;
        }
    }
    LGKMCNT0;
    BARRIER();   // the ONLY barrier: publish cross-wave A tile

    f32x4 acc[2][2];
#pragma unroll
    for (int mi = 0; mi < 2; ++mi)
#pragma unroll
        for (int nj = 0; nj < 2; ++nj) { f32x4 z = {0.f,0.f,0.f,0.f}; acc[mi][nj] = z; }

#pragma unroll
    for (int kc = 0; kc < 16; ++kc) {
        if (kc + 2 < 16) stage_w(kc + 2);      // into buf (kc+2)%3, free
        if (kc < 14)      { VMCNT(4); }        // wait kc's 2 (kc+1,kc+2 in flight)
        else if (kc == 14){ VMCNT(2); }
        else              { VMCNT(0); }
        bf16x8 a[2], b[2];
#pragma unroll
        for (int mi = 0; mi < 2; ++mi)
            a[mi] = *(const bf16x8*)&As[swAs(mi * 16 + lr, kc * 4 + lk)];
#pragma unroll
        for (int nj = 0; nj < 2; ++nj)
            b[nj] = *(const bf16x8*)&Ws[kc % 3][sw64(w * 32 + nj * 16 + lr, lk)];
#pragma unroll
        for (int mi = 0; mi < 2; ++mi)
#pragma unroll
            for (int nj = 0; nj < 2; ++nj)
                acc[mi][nj] = __builtin_amdgcn_mfma_f32_16x16x32_bf16(a[mi], b[nj], acc[mi][nj], 0, 0, 0);
    }

    // epilogue: +bf, relu, x Wc, 16-lane reduce, atomic into out (bc pre-init)
#pragma unroll
    for (int mi = 0; mi < 2; ++mi)
#pragma unroll
        for (int j = 0; j < 4; ++j) {
            float p0 = 0.f, p1 = 0.f;
#pragma unroll
            for (int nj = 0; nj < 2; ++nj) {
                const int col = colbase + nj * 16 + lr;
                const float r = fmaxf(acc[mi][nj][j] + bf[col], 0.f);
                p0 = fmaf(r, Wc[col * 2 + 0], p0);
                p1 = fmaf(r, Wc[col * 2 + 1], p1);
            }
#pragma unroll
            for (int off = 1; off < 16; off <<= 1) {
                p0 += __shfl_xor(p0, off, 64);
                p1 += __shfl_xor(p1, off, 64);
            }
            if (lr == 0) {
                const int row = base + mi * 16 + lk * 4 + j;
                atomicAdd(&out[row * 2 + 0], p0);
                atomicAdd(&out[row * 2 + 1], p1);
            }
        }
}

// ---------------------------------------------------------------------------
extern "C" void kernel_launch(void* const* d_in, const int* in_sizes, int n_in,
                              void* d_out, int out_size, void* d_ws, size_t ws_size,
                              hipStream_t stream)
{
    const float* Xb = (const float*)d_in[0];
    const float* Xc = (const float*)d_in[1];
    // d_in[2] (vec_fcg) intentionally unused: reference source bug reuses cfg.
    const float* Wg = (const float*)d_in[3];
    const float* bg = (const float*)d_in[4];
    const float* W1 = (const float*)d_in[5];
    const float* b1 = (const float*)d_in[6];
    const float* W2 = (const float*)d_in[7];
    const float* b2 = (const float*)d_in[8];
    const float* Wf = (const float*)d_in[9];
    const float* bf = (const float*)d_in[10];
    const float* Wc = (const float*)d_in[11];
    const float* bc = (const float*)d_in[12];
    float* out = (float*)d_out;

    float* ws = (float*)d_ws;
    float* gpart   = ws;                            // [512][8]
    float* cpart   = gpart + 512 * M_EXP;           // [512][8]
    float* sum_out = cpart + 512 * M_EXP;           // [8][256]
    float* cfd     = sum_out + M_EXP * O_DIM;       // [16][4096]
    int*   cnti    = (int*)(cfd + NGRP * N_TOK);    // [16]
    int*   list    = cnti + 16;                     // [16][4096]
    float* cwgt    = (float*)(list + NGRP * N_TOK); // [16][4096]
    int*   invslot = (int*)(cwgt + NGRP * N_TOK);   // [16][4096]
    int*   eidx    = invslot + NGRP * N_TOK;        // [2][4096][2]
    unsigned short* W1T = (unsigned short*)(eidx + 2 * N_TOK * 2); // [8][256][512]
    unsigned short* W2T = W1T + (size_t)M_EXP * H_DIM * D_IN;      // [8][256][256]
    unsigned short* WfT = W2T + (size_t)M_EXP * O_DIM * H_DIM;     // [512][512]
    unsigned short* Xbf = WfT + (size_t)F_DIM * 512;               // [2][4096][512]
    unsigned short* Ybuf = Xbf + (size_t)2 * N_TOK * D_IN;         // [16][4096][256]

    prep_gate_kernel<<<dim3(2337), 256, 0, stream>>>(
        Xb, Xc, Wg, bg, W1, W2, Wf, bc,
        W1T, W2T, WfT, Xbf,
        cfd, eidx, gpart, cpart, sum_out, out);

    compact_kernel<<<dim3(NGRP), 256, 0, stream>>>(cfd, cnti, list, cwgt, invslot);

    hy_gemm_kernel<<<dim3(2048), 256, 0, stream>>>(
        Xbf, W1T, W2T, b1, b2, cnti, list, cwgt, Ybuf, sum_out);

    fuse_cls_loss_kernel<<<dim3(129, 4), 256, 0, stream>>>(
        Ybuf, eidx, invslot, WfT, bf, Wc, gpart, cpart, sum_out, out);
}

// Round 14
// 74.817 us; speedup vs baseline: 1.0376x; 1.0376x over previous
//
#include <hip/hip_runtime.h>
#include <hip/hip_bf16.h>

// Problem constants: N=4096, D=512, H=256, O=256, M=8, K=2, F=512, C=2
#define N_TOK 4096
#define D_IN  512
#define H_DIM 256
#define O_DIM 256
#define M_EXP 8
#define F_DIM 512
#define NGRP  16          // 2 modalities x 8 experts

typedef __attribute__((ext_vector_type(8))) short bf16x8;   // 8 bf16 = 4 VGPRs
typedef __attribute__((ext_vector_type(4))) float f32x4;    // MFMA C/D frag

#define VMCNT(n)  asm volatile("s_waitcnt vmcnt(" #n ")" ::: "memory")
#define LGKMCNT0  asm volatile("s_waitcnt lgkmcnt(0)" ::: "memory")
#define BARRIER() __builtin_amdgcn_s_barrier()

// RNE f32 -> bf16 bits
__device__ __forceinline__ unsigned short f2bf(float f) {
    unsigned int u = __float_as_uint(f);
    u = (u + 0x7FFFu + ((u >> 16) & 1u)) >> 16;
    return (unsigned short)u;
}
__device__ __forceinline__ float b2f(unsigned short u) {
    return __uint_as_float((unsigned int)u << 16);
}

// async global->LDS, 16B per lane; LDS dest wave-uniform base + lane*16
__device__ __forceinline__ void gload_lds16(const void* g, void* l) {
    __builtin_amdgcn_global_load_lds(
        (const __attribute__((address_space(1))) unsigned int*)g,
        (__attribute__((address_space(3))) unsigned int*)l, 16, 0, 0);
}

// Swizzled LDS byte offset for [R][32 bf16] tiles (64B rows, 4x16B slots).
__device__ __forceinline__ int sw64(int row, int lslot) {
    return row * 64 + ((lslot ^ ((row >> 1) & 3)) << 4);
}
// 512B rows (32x16B slots): slot ^= row&7.
__device__ __forceinline__ int swHs(int row, int lslot) {
    return row * 512 + ((lslot ^ (row & 7)) << 4);
}
// 1024B rows (64x16B slots): slot ^= row&7.
__device__ __forceinline__ int swAs(int row, int lslot) {
    return row * 1024 + ((lslot ^ (row & 7)) << 4);
}

// ---------------------------------------------------------------------------
// Kernel 1 (merged): weight transposes + WfT fold + out init + sum_out zero +
// gating. Gating: 512 blocks, 16 tokens each (4/wave, Wg reused in regs;
// lanes 0-3 process one token each after the butterfly). Reduce tree and
// per-lane d-mapping identical to earlier rounds -> logits bit-identical.
// ---------------------------------------------------------------------------
__global__ __launch_bounds__(256) void prep_gate_kernel(
    const float* __restrict__ Xb, const float* __restrict__ Xc,
    const float* __restrict__ Wg, const float* __restrict__ bg,
    const float* __restrict__ W1, const float* __restrict__ W2,
    const float* __restrict__ Wf, const float* __restrict__ bc,
    unsigned short* __restrict__ W1T, unsigned short* __restrict__ W2T,
    unsigned short* __restrict__ WfT, unsigned short* __restrict__ Xbf,
    float* __restrict__ cfd, int* __restrict__ eidx,
    float* __restrict__ gpart, float* __restrict__ cpart,
    float* __restrict__ sum_out, float* __restrict__ out)
{
    __shared__ float tile[32][33];
    __shared__ float s_g[M_EXP];
    __shared__ float s_c[M_EXP];
    const int bx = blockIdx.x;
    const int tr = threadIdx.x >> 3, q = threadIdx.x & 7;

    if (bx < 1024) {            // W1 [8][512][256] -> W1T [8][256][512]
        const int e = bx >> 7, tidx = bx & 127;
        const int r0 = (tidx >> 3) * 32, c0 = (tidx & 7) * 32;
        const float* s = W1 + (size_t)e * 512 * 256;
        unsigned short* d = W1T + (size_t)e * 512 * 256;
        *(float4*)&tile[tr][q * 4] = *(const float4*)&s[(size_t)(r0 + tr) * 256 + c0 + q * 4];
        __syncthreads();
        ushort4 o;
        o.x = f2bf(tile[q*4+0][tr]); o.y = f2bf(tile[q*4+1][tr]);
        o.z = f2bf(tile[q*4+2][tr]); o.w = f2bf(tile[q*4+3][tr]);
        *(ushort4*)&d[(size_t)(c0 + tr) * 512 + r0 + q * 4] = o;
    } else if (bx < 1536) {     // W2 [8][256][256] -> W2T [8][256][256]
        const int idx = bx - 1024;
        const int e = idx >> 6, tidx = idx & 63;
        const int r0 = (tidx >> 3) * 32, c0 = (tidx & 7) * 32;
        const float* s = W2 + (size_t)e * 256 * 256;
        unsigned short* d = W2T + (size_t)e * 256 * 256;
        *(float4*)&tile[tr][q * 4] = *(const float4*)&s[(size_t)(r0 + tr) * 256 + c0 + q * 4];
        __syncthreads();
        ushort4 o;
        o.x = f2bf(tile[q*4+0][tr]); o.y = f2bf(tile[q*4+1][tr]);
        o.z = f2bf(tile[q*4+2][tr]); o.w = f2bf(tile[q*4+3][tr]);
        *(ushort4*)&d[(size_t)(c0 + tr) * 256 + r0 + q * 4] = o;
    } else if (bx < 1792) {     // WfT_eff[f][j] = Wf[j][f] + (j>=256 ? Wf[j+256][f] : 0)
        const int idx = bx - 1536;
        const int j0 = (idx >> 4) * 32, f0 = (idx & 15) * 32;
        float4 v = *(const float4*)&Wf[(size_t)(j0 + tr) * F_DIM + f0 + q * 4];
        if (j0 >= 256) {
            const float4 v2 = *(const float4*)&Wf[(size_t)(j0 + tr + 256) * F_DIM + f0 + q * 4];
            v.x += v2.x; v.y += v2.y; v.z += v2.z; v.w += v2.w;
        }
        *(float4*)&tile[tr][q * 4] = v;
        __syncthreads();
        ushort4 o;
        o.x = f2bf(tile[q*4+0][tr]); o.y = f2bf(tile[q*4+1][tr]);
        o.z = f2bf(tile[q*4+2][tr]); o.w = f2bf(tile[q*4+3][tr]);
        *(ushort4*)&WfT[(size_t)(f0 + tr) * 512 + j0 + q * 4] = o;
    } else if (bx < 1824) {     // out init
        const int i = (bx - 1792) * 256 + threadIdx.x;
        out[i] = bc[i & 1];
    } else if (bx < 1825) {     // zero sum_out
#pragma unroll
        for (int k = 0; k < 8; ++k) sum_out[threadIdx.x * 8 + k] = 0.f;
    } else {                    // ---------------- gating: 16 tokens/block ----------------
        const int idx = bx - 1825;          // [0, 512)
        const int mod = idx >> 8;
        const int b = idx & 255;
        const float* X = mod ? Xc : Xb;
        const int wave = threadIdx.x >> 6;
        const int lane = threadIdx.x & 63;
        const int n0 = b * 16 + wave * 4;   // 4 tokens per wave

        if (threadIdx.x < M_EXP) { s_g[threadIdx.x] = 0.f; s_c[threadIdx.x] = 0.f; }
        __syncthreads();

        float acc[4][M_EXP];
#pragma unroll
        for (int j = 0; j < 4; ++j)
#pragma unroll
            for (int m = 0; m < M_EXP; ++m) acc[j][m] = 0.f;

#pragma unroll
        for (int k = 0; k < 8; ++k) {
            const int d = lane + 64 * k;
            float wr[M_EXP];
#pragma unroll
            for (int m = 0; m < M_EXP; ++m) wr[m] = Wg[d * M_EXP + m];
#pragma unroll
            for (int j = 0; j < 4; ++j) {
                const float xv = X[(size_t)(n0 + j) * D_IN + d];
                Xbf[(size_t)mod * N_TOK * D_IN + (size_t)(n0 + j) * D_IN + d] = f2bf(xv);
#pragma unroll
                for (int m = 0; m < M_EXP; ++m) acc[j][m] += xv * wr[m];
            }
        }
#pragma unroll
        for (int off = 1; off < 64; off <<= 1) {
#pragma unroll
            for (int j = 0; j < 4; ++j)
#pragma unroll
                for (int m = 0; m < M_EXP; ++m) acc[j][m] += __shfl_xor(acc[j][m], off, 64);
        }

        // lanes 0-3: each processes token j=lane (all lanes have full sums)
        if (lane < 4) {
            const int j = lane;
            const int n = n0 + j;
            float g[M_EXP];
            float mx = -1e30f;
#pragma unroll
            for (int m = 0; m < M_EXP; ++m) { g[m] = acc[j][m] + bg[m]; mx = fmaxf(mx, g[m]); }
            float es = 0.f;
#pragma unroll
            for (int m = 0; m < M_EXP; ++m) { g[m] = expf(g[m] - mx); es += g[m]; }
            const float inv = 1.f / es;
#pragma unroll
            for (int m = 0; m < M_EXP; ++m) g[m] *= inv;

            int i0 = 0; float v0 = g[0];
#pragma unroll
            for (int m = 1; m < M_EXP; ++m) if (g[m] > v0) { v0 = g[m]; i0 = m; }
            int i1 = -1; float v1 = -1e30f;
#pragma unroll
            for (int m = 0; m < M_EXP; ++m) if (m != i0 && g[m] > v1) { v1 = g[m]; i1 = m; }

            const float wn = 1.f / (v0 + v1);
#pragma unroll
            for (int m = 0; m < M_EXP; ++m) {
                const float cv = (m == i0) ? v0 * wn : (m == i1) ? v1 * wn : 0.f;
                cfd[(size_t)(mod * M_EXP + m) * N_TOK + n] = cv;
            }
            eidx[(mod * N_TOK + n) * 2 + 0] = i0;
            eidx[(mod * N_TOK + n) * 2 + 1] = i1;
#pragma unroll
            for (int m = 0; m < M_EXP; ++m) atomicAdd(&s_g[m], g[m]);
            atomicAdd(&s_c[i0], 1.f);
            atomicAdd(&s_c[i1], 1.f);
        }
        __syncthreads();
        if (threadIdx.x < M_EXP) {
            gpart[idx * M_EXP + threadIdx.x] = s_g[threadIdx.x];   // [512][8]
            cpart[idx * M_EXP + threadIdx.x] = s_c[threadIdx.x];
        }
    }
}

// ---------------------------------------------------------------------------
// Compaction: one block per group. Prefix-sum over cfd[g][*] -> token-ordered
// list/cwgt, inverse map invslot[g][n], count, pad to 32 multiple.
// ---------------------------------------------------------------------------
__global__ __launch_bounds__(256) void compact_kernel(
    const float* __restrict__ cfd, int* __restrict__ cnti,
    int* __restrict__ list, float* __restrict__ cwgt, int* __restrict__ invslot)
{
    __shared__ int scnt[256];
    const int g = blockIdx.x;
    const int t = threadIdx.x;
    float v[16];
    int cnt = 0;
#pragma unroll
    for (int k = 0; k < 16; ++k) {
        v[k] = cfd[(size_t)g * N_TOK + t * 16 + k];
        cnt += (v[k] > 0.f) ? 1 : 0;
    }
    scnt[t] = cnt;
    __syncthreads();
    for (int off = 1; off < 256; off <<= 1) {
        const int y = (t >= off) ? scnt[t - off] : 0;
        __syncthreads();
        scnt[t] += y;
        __syncthreads();
    }
    const int total = scnt[255];
    int pos = scnt[t] - cnt;                 // exclusive prefix
#pragma unroll
    for (int k = 0; k < 16; ++k) {
        if (v[k] > 0.f) {
            const int n = t * 16 + k;
            list[g * N_TOK + pos] = n;
            cwgt[g * N_TOK + pos] = v[k];
            invslot[g * N_TOK + n] = pos;
            ++pos;
        }
    }
    const int padded = (total + 31) & ~31;
    for (int i = total + t; i < padded; i += 256) {
        list[g * N_TOK + i] = 0;
        cwgt[g * N_TOK + i] = 0.f;
    }
    if (t == 0) cnti[g] = total;
}

// ---------------------------------------------------------------------------
// Fused gathered expert kernel (unchanged from round 12, the 21µs winner).
// ---------------------------------------------------------------------------
__global__ __launch_bounds__(256, 4) void hy_gemm_kernel(
    const unsigned short* __restrict__ Xbf,    // [2][4096][512] bf16
    const unsigned short* __restrict__ W1T,    // [8][256][512] bf16
    const unsigned short* __restrict__ W2T,    // [8][256][256] bf16
    const float* __restrict__ b1, const float* __restrict__ b2,
    const int* __restrict__ cnti, const int* __restrict__ list,
    const float* __restrict__ cwgt,
    unsigned short* __restrict__ Ybuf,         // [16][4096][256] bf16 (weighted)
    float* __restrict__ sum_out)
{
    __shared__ __align__(16) char lds[36864];

    const int bid = blockIdx.x;
    const int xcd = bid & 7, r = bid >> 3;
    const int g  = xcd * 2 + (r & 1);
    const int rt = r >> 1;
    const int cnt = cnti[g];
    if (rt * 32 >= cnt) return;
    const int e = g & 7, mod = g >> 3;
    const int r0 = rt * 32;

    const int t = threadIdx.x;
    const int w = t >> 6, l = t & 63;
    const int lr = l & 15, lk = l >> 4;
    const int wcol = w * 64;

    const unsigned short* w1p = W1T + (size_t)e * H_DIM * D_IN;
    const unsigned short* w2p = W2T + (size_t)e * O_DIM * H_DIM;

    float bv1[4], bv2[4];
#pragma unroll
    for (int nj = 0; nj < 4; ++nj) {
        bv1[nj] = b1[e * 256 + wcol + nj * 16 + lr];
        bv2[nj] = b2[e * 256 + wcol + nj * 16 + lr];
    }

    const unsigned short* aptr = nullptr;
    if (w < 2) {
        const int arow = w * 16 + (l >> 2);
        const int ls = (l & 3) ^ ((arow >> 1) & 3);
        const int n = list[g * N_TOK + r0 + arow];
        aptr = Xbf + (size_t)mod * N_TOK * D_IN + (size_t)n * 512 + ls * 8;
    }
    const int brl = l >> 2;
    const int bp = l & 3;

    f32x4 acc[2][4];
#pragma unroll
    for (int mi = 0; mi < 2; ++mi)
#pragma unroll
        for (int nj = 0; nj < 4; ++nj) { f32x4 z = {0.f,0.f,0.f,0.f}; acc[mi][nj] = z; }

    for (int kc = 0; kc < 16; ++kc) {
        if (w < 2) gload_lds16(aptr + kc * 32, lds + w * 1024);
#pragma unroll
        for (int s = 0; s < 4; ++s) {
            const int row = w * 64 + s * 16 + brl;
            const int ls = bp ^ ((row >> 1) & 3);
            gload_lds16(w1p + (size_t)row * 512 + kc * 32 + ls * 8,
                        lds + 2048 + w * 4096 + s * 1024);
        }
        __syncthreads();
        bf16x8 a[2], b[4];
#pragma unroll
        for (int mi = 0; mi < 2; ++mi)
            a[mi] = *(const bf16x8*)(lds + sw64(mi * 16 + lr, lk));
#pragma unroll
        for (int nj = 0; nj < 4; ++nj)
            b[nj] = *(const bf16x8*)(lds + 2048 + sw64(wcol + nj * 16 + lr, lk));
#pragma unroll
        for (int mi = 0; mi < 2; ++mi)
#pragma unroll
            for (int nj = 0; nj < 4; ++nj)
                acc[mi][nj] = __builtin_amdgcn_mfma_f32_16x16x32_bf16(a[mi], b[nj], acc[mi][nj], 0, 0, 0);
        __syncthreads();
    }

#pragma unroll
    for (int mi = 0; mi < 2; ++mi)
#pragma unroll
        for (int nj = 0; nj < 4; ++nj) {
            const int col = wcol + nj * 16 + lr;
            const int cslot = col >> 3;
            const int cbyte = (col & 7) * 2;
#pragma unroll
            for (int j = 0; j < 4; ++j) {
                const int row = mi * 16 + lk * 4 + j;
                *(unsigned short*)(lds + 18432 + row * 512 + ((cslot ^ (row & 7)) << 4) + cbyte) =
                    f2bf(fmaxf(acc[mi][nj][j] + bv1[nj], 0.f));
            }
        }
#pragma unroll
    for (int mi = 0; mi < 2; ++mi)
#pragma unroll
        for (int nj = 0; nj < 4; ++nj) { f32x4 z = {0.f,0.f,0.f,0.f}; acc[mi][nj] = z; }

    for (int kc = 0; kc < 8; ++kc) {
#pragma unroll
        for (int s = 0; s < 4; ++s) {
            const int row = w * 64 + s * 16 + brl;
            const int ls = bp ^ ((row >> 1) & 3);
            gload_lds16(w2p + (size_t)row * 256 + kc * 32 + ls * 8,
                        lds + 2048 + w * 4096 + s * 1024);
        }
        __syncthreads();
        bf16x8 a[2], b[4];
#pragma unroll
        for (int mi = 0; mi < 2; ++mi)
            a[mi] = *(const bf16x8*)(lds + 18432 + swHs(mi * 16 + lr, kc * 4 + lk));
#pragma unroll
        for (int nj = 0; nj < 4; ++nj)
            b[nj] = *(const bf16x8*)(lds + 2048 + sw64(wcol + nj * 16 + lr, lk));
#pragma unroll
        for (int mi = 0; mi < 2; ++mi)
#pragma unroll
            for (int nj = 0; nj < 4; ++nj)
                acc[mi][nj] = __builtin_amdgcn_mfma_f32_16x16x32_bf16(a[mi], b[nj], acc[mi][nj], 0, 0, 0);
        __syncthreads();
    }

    float sacc[4] = {0.f, 0.f, 0.f, 0.f};
#pragma unroll
    for (int mi = 0; mi < 2; ++mi)
#pragma unroll
        for (int j2 = 0; j2 < 4; ++j2) {
            const int row = mi * 16 + lk * 4 + j2;
            const float wv = cwgt[g * N_TOK + r0 + row];
            const bool valid = wv > 0.f;
#pragma unroll
            for (int nj = 0; nj < 4; ++nj) {
                const float v = acc[mi][nj][j2] + bv2[nj];
                if (valid) sacc[nj] += v;
                const int col = wcol + nj * 16 + lr;
                *(unsigned short*)(lds + row * 512 + col * 2) = f2bf(wv * v);
            }
        }
    __syncthreads();
#pragma unroll
    for (int q2 = 0; q2 < 4; ++q2) {
        const int u = q2 * 256 + t;
        const int row = u >> 5, cs = u & 31;
        *(bf16x8*)(Ybuf + (((size_t)g * N_TOK + r0 + row) * 256 + cs * 8)) =
            *(const bf16x8*)(lds + u * 16);
    }
#pragma unroll
    for (int nj = 0; nj < 4; ++nj) {
        sacc[nj] += __shfl_xor(sacc[nj], 16, 64);
        sacc[nj] += __shfl_xor(sacc[nj], 32, 64);
    }
    if (lk == 0) {
        const float modw = mod ? 2.f : 1.f;
#pragma unroll
        for (int nj = 0; nj < 4; ++nj)
            atomicAdd(&sum_out[e * O_DIM + wcol + nj * 16 + lr], sacc[nj] * modw);
    }
}

// ---------------------------------------------------------------------------
// Fusion + classifier (x<128) + losses (block x==128,y==0). Exact round-12
// fuse structure (BN=256, grid 129x2); loss reduction updated for [512][8].
// ---------------------------------------------------------------------------
__global__ __launch_bounds__(256, 2) void fuse_cls_loss_kernel(
    const unsigned short* __restrict__ Ybuf,
    const int* __restrict__ eidx, const int* __restrict__ invslot,
    const unsigned short* __restrict__ WfT, const float* __restrict__ bf,
    const float* __restrict__ Wc,
    const float* __restrict__ gpart, const float* __restrict__ cpart,
    const float* __restrict__ sum_out, float* __restrict__ out)
{
    __shared__ __align__(16) char As[32 * 1024];
    __shared__ __align__(16) char Ws[2][16384];
    __shared__ float avg[M_EXP][O_DIM];
    __shared__ float partl[256];
    __shared__ float rho_s[M_EXP], rhohat_s[M_EXP];
    __shared__ float simv[28], prs[28];

    const int t = threadIdx.x;

    if (blockIdx.x == 128) {                       // ---------- loss ----------
        if (blockIdx.y != 0) return;
        const int e = t & 7, grp = t >> 3;         // gpart is [512][8]
        float sg = 0.f, sc = 0.f;
        for (int b2 = grp * 16; b2 < grp * 16 + 16; ++b2) {
            const float wgt = (b2 < 256) ? 1.f : 2.f;
            sg += wgt * gpart[b2 * 8 + e];
            sc += wgt * cpart[b2 * 8 + e];
        }
        partl[t] = sg; __syncthreads();
        if (t < 8) { float s = 0.f; for (int g2 = 0; g2 < 32; ++g2) s += partl[t + 8 * g2]; rhohat_s[t] = s; }
        __syncthreads();
        partl[t] = sc; __syncthreads();
        if (t < 8) { float s = 0.f; for (int g2 = 0; g2 < 32; ++g2) s += partl[t + 8 * g2]; rho_s[t] = s; }
        __syncthreads();
        for (int idx = t; idx < M_EXP * O_DIM; idx += 256)
            avg[idx >> 8][idx & 255] = sum_out[idx] / fmaxf(rho_s[idx >> 8], 1.f);
        __syncthreads();
        if (t < 28) {
            int a = 0, p = t;
            while (p >= 7 - a) { p -= 7 - a; ++a; }
            const int b = a + 1 + p;
            float d2 = 0.f;
            for (int o = 0; o < O_DIM; ++o) {
                const float df = avg[a][o] - avg[b][o];
                d2 = fmaf(df, df, d2);
            }
            const bool pr = (rho_s[a] > 0.f) && (rho_s[b] > 0.f);
            simv[t] = pr ? expf(-0.5f * d2) : 0.f;
            prs[t]  = pr ? 1.f : 0.f;
        }
        __syncthreads();
        if (t == 0) {
            float s = 0.f, np = 0.f;
            for (int p = 0; p < 28; ++p) { s += simv[p]; np += prs[p]; }
            out[N_TOK * 2 + 0] = -s / fmaxf(np, 1.f);
            float eq = 0.f;
            for (int m = 0; m < M_EXP; ++m) eq = fmaf(rho_s[m], rhohat_s[m], eq);
            out[N_TOK * 2 + 1] = eq / (float)M_EXP;
        }
        return;
    }

    // ---------- fusion + classifier ----------
    const int w = t >> 6, l = t & 63;
    const int lr = l & 15, lk = l >> 4;
    const int base = blockIdx.x * 32;
    const int half = blockIdx.y;
    const int colbase = half * 256 + w * 64;
    const unsigned short* wfp = WfT + (size_t)half * 256 * 512;

    const int wrl = l >> 2;
    const int wp = l & 3;
    auto stage_w = [&](int kc, int buf) {
#pragma unroll
        for (int s2 = 0; s2 < 4; ++s2) {
            const int row = w * 64 + s2 * 16 + wrl;
            const int lslot = wp ^ ((row >> 1) & 3);
            gload_lds16(wfp + (size_t)row * 512 + kc * 32 + lslot * 8,
                        &Ws[buf][w * 4096 + s2 * 1024]);
        }
    };

    stage_w(0, 0);

    {   // A stage: combined[32][512] = gathered sums of 2 weighted Y rows
        const int r = t >> 3;
        const int c0 = (t & 7) * 64;
        const int n = base + r;
        const int mod = c0 >> 8;
        const int cc = c0 & 255;
        const int i0 = eidx[(mod * N_TOK + n) * 2 + 0];
        const int i1 = eidx[(mod * N_TOK + n) * 2 + 1];
        const int g0 = mod * M_EXP + i0, g1 = mod * M_EXP + i1;
        const int s0 = invslot[g0 * N_TOK + n];
        const int s1 = invslot[g1 * N_TOK + n];
        const unsigned short* y0 = Ybuf + ((size_t)g0 * N_TOK + s0) * 256 + cc;
        const unsigned short* y1 = Ybuf + ((size_t)g1 * N_TOK + s1) * 256 + cc;
#pragma unroll
        for (int q = 0; q < 8; ++q) {
            const bf16x8 a0 = *(const bf16x8*)(y0 + q * 8);
            const bf16x8 a1 = *(const bf16x8*)(y1 + q * 8);
            bf16x8 p;
#pragma unroll
            for (int j = 0; j < 8; ++j)
                p[j] = (short)f2bf(b2f((unsigned short)a0[j]) + b2f((unsigned short)a1[j]));
            *(bf16x8*)&As[swAs(r, (t & 7) * 8 + q)] = p;
        }
    }
    LGKMCNT0;

    f32x4 acc[2][4];
#pragma unroll
    for (int mi = 0; mi < 2; ++mi)
#pragma unroll
        for (int nj = 0; nj < 4; ++nj) { f32x4 z = {0.f,0.f,0.f,0.f}; acc[mi][nj] = z; }

    int cur = 0;
#pragma unroll
    for (int kc = 0; kc < 16; ++kc) {
        const int nb = cur ^ 1;
        if (kc < 15) { stage_w(kc + 1, nb); VMCNT(4); }
        else         { VMCNT(0); }
        BARRIER();
        bf16x8 a[2], b[4];
#pragma unroll
        for (int mi = 0; mi < 2; ++mi)
            a[mi] = *(const bf16x8*)&As[swAs(mi * 16 + lr, kc * 4 + lk)];
#pragma unroll
        for (int nj = 0; nj < 4; ++nj)
            b[nj] = *(const bf16x8*)&Ws[cur][sw64(w * 64 + nj * 16 + lr, lk)];
#pragma unroll
        for (int mi = 0; mi < 2; ++mi)
#pragma unroll
            for (int nj = 0; nj < 4; ++nj)
                acc[mi][nj] = __builtin_amdgcn_mfma_f32_16x16x32_bf16(a[mi], b[nj], acc[mi][nj], 0, 0, 0);
        BARRIER();
        cur = nb;
    }

#pragma unroll
    for (int mi = 0; mi < 2; ++mi)
#pragma unroll
        for (int j = 0; j < 4; ++j) {
            float p0 = 0.f, p1 = 0.f;
#pragma unroll
            for (int nj = 0; nj < 4; ++nj) {
                const int col = colbase + nj * 16 + lr;
                const float r = fmaxf(acc[mi][nj][j] + bf[col], 0.f);
                p0 = fmaf(r, Wc[col * 2 + 0], p0);
                p1 = fmaf(r, Wc[col * 2 + 1], p1);
            }
#pragma unroll
            for (int off = 1; off < 16; off <<= 1) {
                p0 += __shfl_xor(p0, off, 64);
                p1 += __shfl_xor(p1, off, 64);
            }
            if (lr == 0) {
                const int row = base + mi * 16 + lk * 4 + j;
                atomicAdd(&out[row * 2 + 0], p0);
                atomicAdd(&out[row * 2 + 1], p1);
            }
        }
}

// ---------------------------------------------------------------------------
extern "C" void kernel_launch(void* const* d_in, const int* in_sizes, int n_in,
                              void* d_out, int out_size, void* d_ws, size_t ws_size,
                              hipStream_t stream)
{
    const float* Xb = (const float*)d_in[0];
    const float* Xc = (const float*)d_in[1];
    // d_in[2] (vec_fcg) intentionally unused: reference source bug reuses cfg.
    const float* Wg = (const float*)d_in[3];
    const float* bg = (const float*)d_in[4];
    const float* W1 = (const float*)d_in[5];
    const float* b1 = (const float*)d_in[6];
    const float* W2 = (const float*)d_in[7];
    const float* b2 = (const float*)d_in[8];
    const float* Wf = (const float*)d_in[9];
    const float* bf = (const float*)d_in[10];
    const float* Wc = (const float*)d_in[11];
    const float* bc = (const float*)d_in[12];
    float* out = (float*)d_out;

    float* ws = (float*)d_ws;
    float* gpart   = ws;                            // [512][8]
    float* cpart   = gpart + 512 * M_EXP;           // [512][8]
    float* sum_out = cpart + 512 * M_EXP;           // [8][256]
    float* cfd     = sum_out + M_EXP * O_DIM;       // [16][4096]
    int*   cnti    = (int*)(cfd + NGRP * N_TOK);    // [16]
    int*   list    = cnti + 16;                     // [16][4096]
    float* cwgt    = (float*)(list + NGRP * N_TOK); // [16][4096]
    int*   invslot = (int*)(cwgt + NGRP * N_TOK);   // [16][4096]
    int*   eidx    = invslot + NGRP * N_TOK;        // [2][4096][2]
    unsigned short* W1T = (unsigned short*)(eidx + 2 * N_TOK * 2); // [8][256][512]
    unsigned short* W2T = W1T + (size_t)M_EXP * H_DIM * D_IN;      // [8][256][256]
    unsigned short* WfT = W2T + (size_t)M_EXP * O_DIM * H_DIM;     // [512][512]
    unsigned short* Xbf = WfT + (size_t)F_DIM * 512;               // [2][4096][512]
    unsigned short* Ybuf = Xbf + (size_t)2 * N_TOK * D_IN;         // [16][4096][256]

    prep_gate_kernel<<<dim3(2337), 256, 0, stream>>>(
        Xb, Xc, Wg, bg, W1, W2, Wf, bc,
        W1T, W2T, WfT, Xbf,
        cfd, eidx, gpart, cpart, sum_out, out);

    compact_kernel<<<dim3(NGRP), 256, 0, stream>>>(cfd, cnti, list, cwgt, invslot);

    hy_gemm_kernel<<<dim3(2048), 256, 0, stream>>>(
        Xbf, W1T, W2T, b1, b2, cnti, list, cwgt, Ybuf, sum_out);

    fuse_cls_loss_kernel<<<dim3(129, 2), 256, 0, stream>>>(
        Ybuf, eidx, invslot, WfT, bf, Wc, gpart, cpart, sum_out, out);
}

// Round 15
// 64.516 us; speedup vs baseline: 1.2033x; 1.1597x over previous
//
#include <hip/hip_runtime.h>
#include <hip/hip_bf16.h>

// Problem constants: N=4096, D=512, H=256, O=256, M=8, K=2, F=512, C=2
#define N_TOK 4096
#define D_IN  512
#define H_DIM 256
#define O_DIM 256
#define M_EXP 8
#define F_DIM 512
#define NGRP  16          // 2 modalities x 8 experts

typedef __attribute__((ext_vector_type(8))) short bf16x8;   // 8 bf16 = 4 VGPRs
typedef __attribute__((ext_vector_type(4))) float f32x4;    // MFMA C/D frag

#define VMCNT(n)  asm volatile("s_waitcnt vmcnt(" #n ")" ::: "memory")
#define LGKMCNT0  asm volatile("s_waitcnt lgkmcnt(0)" ::: "memory")
#define BARRIER() __builtin_amdgcn_s_barrier()

// RNE f32 -> bf16 bits
__device__ __forceinline__ unsigned short f2bf(float f) {
    unsigned int u = __float_as_uint(f);
    u = (u + 0x7FFFu + ((u >> 16) & 1u)) >> 16;
    return (unsigned short)u;
}
__device__ __forceinline__ float b2f(unsigned short u) {
    return __uint_as_float((unsigned int)u << 16);
}

// async global->LDS, 16B per lane; LDS dest wave-uniform base + lane*16
__device__ __forceinline__ void gload_lds16(const void* g, void* l) {
    __builtin_amdgcn_global_load_lds(
        (const __attribute__((address_space(1))) unsigned int*)g,
        (__attribute__((address_space(3))) unsigned int*)l, 16, 0, 0);
}

// Swizzled LDS byte offset for [R][32 bf16] tiles (64B rows, 4x16B slots).
__device__ __forceinline__ int sw64(int row, int lslot) {
    return row * 64 + ((lslot ^ ((row >> 1) & 3)) << 4);
}
// 512B rows (32x16B slots): slot ^= row&7.
__device__ __forceinline__ int swHs(int row, int lslot) {
    return row * 512 + ((lslot ^ (row & 7)) << 4);
}
// 1024B rows (64x16B slots): slot ^= row&7.
__device__ __forceinline__ int swAs(int row, int lslot) {
    return row * 1024 + ((lslot ^ (row & 7)) << 4);
}

// ---------------------------------------------------------------------------
// Kernel 1 (merged): weight transposes + WfT fold + out init + sum_out zero +
// gating. Gating writes dense cfd[16][4096], eidx, Xbf, gate partials.
// (Round-12 configuration: 1 token per wave, 2048 gating blocks — A/B-verified
// faster than the 4-token/wave variant, which was latency-bound.)
// ---------------------------------------------------------------------------
__global__ __launch_bounds__(256) void prep_gate_kernel(
    const float* __restrict__ Xb, const float* __restrict__ Xc,
    const float* __restrict__ Wg, const float* __restrict__ bg,
    const float* __restrict__ W1, const float* __restrict__ W2,
    const float* __restrict__ Wf, const float* __restrict__ bc,
    unsigned short* __restrict__ W1T, unsigned short* __restrict__ W2T,
    unsigned short* __restrict__ WfT, unsigned short* __restrict__ Xbf,
    float* __restrict__ cfd, int* __restrict__ eidx,
    float* __restrict__ gpart, float* __restrict__ cpart,
    float* __restrict__ sum_out, float* __restrict__ out)
{
    __shared__ float tile[32][33];
    __shared__ float s_g[M_EXP];
    __shared__ float s_c[M_EXP];
    const int bx = blockIdx.x;
    const int tr = threadIdx.x >> 3, q = threadIdx.x & 7;

    if (bx < 1024) {            // W1 [8][512][256] -> W1T [8][256][512]
        const int e = bx >> 7, tidx = bx & 127;
        const int r0 = (tidx >> 3) * 32, c0 = (tidx & 7) * 32;
        const float* s = W1 + (size_t)e * 512 * 256;
        unsigned short* d = W1T + (size_t)e * 512 * 256;
        *(float4*)&tile[tr][q * 4] = *(const float4*)&s[(size_t)(r0 + tr) * 256 + c0 + q * 4];
        __syncthreads();
        ushort4 o;
        o.x = f2bf(tile[q*4+0][tr]); o.y = f2bf(tile[q*4+1][tr]);
        o.z = f2bf(tile[q*4+2][tr]); o.w = f2bf(tile[q*4+3][tr]);
        *(ushort4*)&d[(size_t)(c0 + tr) * 512 + r0 + q * 4] = o;
    } else if (bx < 1536) {     // W2 [8][256][256] -> W2T [8][256][256]
        const int idx = bx - 1024;
        const int e = idx >> 6, tidx = idx & 63;
        const int r0 = (tidx >> 3) * 32, c0 = (tidx & 7) * 32;
        const float* s = W2 + (size_t)e * 256 * 256;
        unsigned short* d = W2T + (size_t)e * 256 * 256;
        *(float4*)&tile[tr][q * 4] = *(const float4*)&s[(size_t)(r0 + tr) * 256 + c0 + q * 4];
        __syncthreads();
        ushort4 o;
        o.x = f2bf(tile[q*4+0][tr]); o.y = f2bf(tile[q*4+1][tr]);
        o.z = f2bf(tile[q*4+2][tr]); o.w = f2bf(tile[q*4+3][tr]);
        *(ushort4*)&d[(size_t)(c0 + tr) * 256 + r0 + q * 4] = o;
    } else if (bx < 1792) {     // WfT_eff[f][j] = Wf[j][f] + (j>=256 ? Wf[j+256][f] : 0)
        const int idx = bx - 1536;
        const int j0 = (idx >> 4) * 32, f0 = (idx & 15) * 32;
        float4 v = *(const float4*)&Wf[(size_t)(j0 + tr) * F_DIM + f0 + q * 4];
        if (j0 >= 256) {
            const float4 v2 = *(const float4*)&Wf[(size_t)(j0 + tr + 256) * F_DIM + f0 + q * 4];
            v.x += v2.x; v.y += v2.y; v.z += v2.z; v.w += v2.w;
        }
        *(float4*)&tile[tr][q * 4] = v;
        __syncthreads();
        ushort4 o;
        o.x = f2bf(tile[q*4+0][tr]); o.y = f2bf(tile[q*4+1][tr]);
        o.z = f2bf(tile[q*4+2][tr]); o.w = f2bf(tile[q*4+3][tr]);
        *(ushort4*)&WfT[(size_t)(f0 + tr) * 512 + j0 + q * 4] = o;
    } else if (bx < 1824) {     // out init
        const int i = (bx - 1792) * 256 + threadIdx.x;
        out[i] = bc[i & 1];
    } else if (bx < 1825) {     // zero sum_out
#pragma unroll
        for (int k = 0; k < 8; ++k) sum_out[threadIdx.x * 8 + k] = 0.f;
    } else {                    // ---------------- gating ----------------
        const int idx = bx - 1825;
        const int mod = idx >> 10;
        const int b = idx & 1023;
        const float* X = mod ? Xc : Xb;
        const int wave = threadIdx.x >> 6;
        const int lane = threadIdx.x & 63;
        const int n = b * 4 + wave;

        if (threadIdx.x < M_EXP) { s_g[threadIdx.x] = 0.f; s_c[threadIdx.x] = 0.f; }
        __syncthreads();

        float acc[M_EXP] = {0.f,0.f,0.f,0.f,0.f,0.f,0.f,0.f};
        const float* xrow = X + (size_t)n * D_IN;
        unsigned short* xb = Xbf + (size_t)mod * N_TOK * D_IN + (size_t)n * D_IN;
#pragma unroll
        for (int k = 0; k < 8; ++k) {
            const int d = lane + 64 * k;
            const float xv = xrow[d];
            xb[d] = f2bf(xv);
            const float* wr = Wg + d * M_EXP;
#pragma unroll
            for (int m = 0; m < M_EXP; ++m) acc[m] += xv * wr[m];
        }
#pragma unroll
        for (int off = 1; off < 64; off <<= 1) {
#pragma unroll
            for (int m = 0; m < M_EXP; ++m) acc[m] += __shfl_xor(acc[m], off, 64);
        }
        float g[M_EXP];
        float mx = -1e30f;
#pragma unroll
        for (int m = 0; m < M_EXP; ++m) { g[m] = acc[m] + bg[m]; mx = fmaxf(mx, g[m]); }
        float es = 0.f;
#pragma unroll
        for (int m = 0; m < M_EXP; ++m) { g[m] = expf(g[m] - mx); es += g[m]; }
        const float inv = 1.f / es;
#pragma unroll
        for (int m = 0; m < M_EXP; ++m) g[m] *= inv;

        int i0 = 0; float v0 = g[0];
#pragma unroll
        for (int m = 1; m < M_EXP; ++m) if (g[m] > v0) { v0 = g[m]; i0 = m; }
        int i1 = -1; float v1 = -1e30f;
#pragma unroll
        for (int m = 0; m < M_EXP; ++m) if (m != i0 && g[m] > v1) { v1 = g[m]; i1 = m; }

        if (lane == 0) {
            const float wn = 1.f / (v0 + v1);
#pragma unroll
            for (int m = 0; m < M_EXP; ++m) {
                const float cv = (m == i0) ? v0 * wn : (m == i1) ? v1 * wn : 0.f;
                cfd[(size_t)(mod * M_EXP + m) * N_TOK + n] = cv;
            }
            eidx[(mod * N_TOK + n) * 2 + 0] = i0;
            eidx[(mod * N_TOK + n) * 2 + 1] = i1;
#pragma unroll
            for (int m = 0; m < M_EXP; ++m) atomicAdd(&s_g[m], g[m]);
            atomicAdd(&s_c[i0], 1.f);
            atomicAdd(&s_c[i1], 1.f);
        }
        __syncthreads();
        if (threadIdx.x < M_EXP) {
            gpart[idx * M_EXP + threadIdx.x] = s_g[threadIdx.x];
            cpart[idx * M_EXP + threadIdx.x] = s_c[threadIdx.x];
        }
    }
}

// ---------------------------------------------------------------------------
// Compaction: one block per group. Prefix-sum over cfd[g][*] -> token-ordered
// list/cwgt, inverse map invslot[g][n], count, pad to 32 multiple.
// ---------------------------------------------------------------------------
__global__ __launch_bounds__(256) void compact_kernel(
    const float* __restrict__ cfd, int* __restrict__ cnti,
    int* __restrict__ list, float* __restrict__ cwgt, int* __restrict__ invslot)
{
    __shared__ int scnt[256];
    const int g = blockIdx.x;
    const int t = threadIdx.x;
    float v[16];
    int cnt = 0;
#pragma unroll
    for (int k = 0; k < 16; ++k) {
        v[k] = cfd[(size_t)g * N_TOK + t * 16 + k];
        cnt += (v[k] > 0.f) ? 1 : 0;
    }
    scnt[t] = cnt;
    __syncthreads();
    for (int off = 1; off < 256; off <<= 1) {
        const int y = (t >= off) ? scnt[t - off] : 0;
        __syncthreads();
        scnt[t] += y;
        __syncthreads();
    }
    const int total = scnt[255];
    int pos = scnt[t] - cnt;                 // exclusive prefix
#pragma unroll
    for (int k = 0; k < 16; ++k) {
        if (v[k] > 0.f) {
            const int n = t * 16 + k;
            list[g * N_TOK + pos] = n;
            cwgt[g * N_TOK + pos] = v[k];
            invslot[g * N_TOK + n] = pos;
            ++pos;
        }
    }
    const int padded = (total + 31) & ~31;
    for (int i = total + t; i < padded; i += 256) {
        list[g * N_TOK + i] = 0;
        cwgt[g * N_TOK + i] = 0.f;
    }
    if (t == 0) cnti[g] = total;
}

// ---------------------------------------------------------------------------
// Fused gathered expert kernel (round-12 version).
// ---------------------------------------------------------------------------
__global__ __launch_bounds__(256, 4) void hy_gemm_kernel(
    const unsigned short* __restrict__ Xbf,    // [2][4096][512] bf16
    const unsigned short* __restrict__ W1T,    // [8][256][512] bf16
    const unsigned short* __restrict__ W2T,    // [8][256][256] bf16
    const float* __restrict__ b1, const float* __restrict__ b2,
    const int* __restrict__ cnti, const int* __restrict__ list,
    const float* __restrict__ cwgt,
    unsigned short* __restrict__ Ybuf,         // [16][4096][256] bf16 (weighted)
    float* __restrict__ sum_out)
{
    __shared__ __align__(16) char lds[36864];

    const int bid = blockIdx.x;
    const int xcd = bid & 7, r = bid >> 3;
    const int g  = xcd * 2 + (r & 1);
    const int rt = r >> 1;
    const int cnt = cnti[g];
    if (rt * 32 >= cnt) return;
    const int e = g & 7, mod = g >> 3;
    const int r0 = rt * 32;

    const int t = threadIdx.x;
    const int w = t >> 6, l = t & 63;
    const int lr = l & 15, lk = l >> 4;
    const int wcol = w * 64;

    const unsigned short* w1p = W1T + (size_t)e * H_DIM * D_IN;
    const unsigned short* w2p = W2T + (size_t)e * O_DIM * H_DIM;

    float bv1[4], bv2[4];
#pragma unroll
    for (int nj = 0; nj < 4; ++nj) {
        bv1[nj] = b1[e * 256 + wcol + nj * 16 + lr];
        bv2[nj] = b2[e * 256 + wcol + nj * 16 + lr];
    }

    const unsigned short* aptr = nullptr;
    if (w < 2) {
        const int arow = w * 16 + (l >> 2);
        const int ls = (l & 3) ^ ((arow >> 1) & 3);
        const int n = list[g * N_TOK + r0 + arow];
        aptr = Xbf + (size_t)mod * N_TOK * D_IN + (size_t)n * 512 + ls * 8;
    }
    const int brl = l >> 2;
    const int bp = l & 3;

    f32x4 acc[2][4];
#pragma unroll
    for (int mi = 0; mi < 2; ++mi)
#pragma unroll
        for (int nj = 0; nj < 4; ++nj) { f32x4 z = {0.f,0.f,0.f,0.f}; acc[mi][nj] = z; }

    for (int kc = 0; kc < 16; ++kc) {
        if (w < 2) gload_lds16(aptr + kc * 32, lds + w * 1024);
#pragma unroll
        for (int s = 0; s < 4; ++s) {
            const int row = w * 64 + s * 16 + brl;
            const int ls = bp ^ ((row >> 1) & 3);
            gload_lds16(w1p + (size_t)row * 512 + kc * 32 + ls * 8,
                        lds + 2048 + w * 4096 + s * 1024);
        }
        __syncthreads();
        bf16x8 a[2], b[4];
#pragma unroll
        for (int mi = 0; mi < 2; ++mi)
            a[mi] = *(const bf16x8*)(lds + sw64(mi * 16 + lr, lk));
#pragma unroll
        for (int nj = 0; nj < 4; ++nj)
            b[nj] = *(const bf16x8*)(lds + 2048 + sw64(wcol + nj * 16 + lr, lk));
#pragma unroll
        for (int mi = 0; mi < 2; ++mi)
#pragma unroll
            for (int nj = 0; nj < 4; ++nj)
                acc[mi][nj] = __builtin_amdgcn_mfma_f32_16x16x32_bf16(a[mi], b[nj], acc[mi][nj], 0, 0, 0);
        __syncthreads();
    }

#pragma unroll
    for (int mi = 0; mi < 2; ++mi)
#pragma unroll
        for (int nj = 0; nj < 4; ++nj) {
            const int col = wcol + nj * 16 + lr;
            const int cslot = col >> 3;
            const int cbyte = (col & 7) * 2;
#pragma unroll
            for (int j = 0; j < 4; ++j) {
                const int row = mi * 16 + lk * 4 + j;
                *(unsigned short*)(lds + 18432 + row * 512 + ((cslot ^ (row & 7)) << 4) + cbyte) =
                    f2bf(fmaxf(acc[mi][nj][j] + bv1[nj], 0.f));
            }
        }
#pragma unroll
    for (int mi = 0; mi < 2; ++mi)
#pragma unroll
        for (int nj = 0; nj < 4; ++nj) { f32x4 z = {0.f,0.f,0.f,0.f}; acc[mi][nj] = z; }

    for (int kc = 0; kc < 8; ++kc) {
#pragma unroll
        for (int s = 0; s < 4; ++s) {
            const int row = w * 64 + s * 16 + brl;
            const int ls = bp ^ ((row >> 1) & 3);
            gload_lds16(w2p + (size_t)row * 256 + kc * 32 + ls * 8,
                        lds + 2048 + w * 4096 + s * 1024);
        }
        __syncthreads();
        bf16x8 a[2], b[4];
#pragma unroll
        for (int mi = 0; mi < 2; ++mi)
            a[mi] = *(const bf16x8*)(lds + 18432 + swHs(mi * 16 + lr, kc * 4 + lk));
#pragma unroll
        for (int nj = 0; nj < 4; ++nj)
            b[nj] = *(const bf16x8*)(lds + 2048 + sw64(wcol + nj * 16 + lr, lk));
#pragma unroll
        for (int mi = 0; mi < 2; ++mi)
#pragma unroll
            for (int nj = 0; nj < 4; ++nj)
                acc[mi][nj] = __builtin_amdgcn_mfma_f32_16x16x32_bf16(a[mi], b[nj], acc[mi][nj], 0, 0, 0);
        __syncthreads();
    }

    float sacc[4] = {0.f, 0.f, 0.f, 0.f};
#pragma unroll
    for (int mi = 0; mi < 2; ++mi)
#pragma unroll
        for (int j2 = 0; j2 < 4; ++j2) {
            const int row = mi * 16 + lk * 4 + j2;
            const float wv = cwgt[g * N_TOK + r0 + row];
            const bool valid = wv > 0.f;
#pragma unroll
            for (int nj = 0; nj < 4; ++nj) {
                const float v = acc[mi][nj][j2] + bv2[nj];
                if (valid) sacc[nj] += v;
                const int col = wcol + nj * 16 + lr;
                *(unsigned short*)(lds + row * 512 + col * 2) = f2bf(wv * v);
            }
        }
    __syncthreads();
#pragma unroll
    for (int q2 = 0; q2 < 4; ++q2) {
        const int u = q2 * 256 + t;
        const int row = u >> 5, cs = u & 31;
        *(bf16x8*)(Ybuf + (((size_t)g * N_TOK + r0 + row) * 256 + cs * 8)) =
            *(const bf16x8*)(lds + u * 16);
    }
#pragma unroll
    for (int nj = 0; nj < 4; ++nj) {
        sacc[nj] += __shfl_xor(sacc[nj], 16, 64);
        sacc[nj] += __shfl_xor(sacc[nj], 32, 64);
    }
    if (lk == 0) {
        const float modw = mod ? 2.f : 1.f;
#pragma unroll
        for (int nj = 0; nj < 4; ++nj)
            atomicAdd(&sum_out[e * O_DIM + wcol + nj * 16 + lr], sacc[nj] * modw);
    }
}

// ---------------------------------------------------------------------------
// Fusion + classifier (x<128) + losses (block x==128,y==0). Round-12 version
// (BN=256, grid 129x2, double-buffered Ws with counted VMCNT(4)).
// ---------------------------------------------------------------------------
__global__ __launch_bounds__(256, 2) void fuse_cls_loss_kernel(
    const unsigned short* __restrict__ Ybuf,
    const int* __restrict__ eidx, const int* __restrict__ invslot,
    const unsigned short* __restrict__ WfT, const float* __restrict__ bf,
    const float* __restrict__ Wc,
    const float* __restrict__ gpart, const float* __restrict__ cpart,
    const float* __restrict__ sum_out, float* __restrict__ out)
{
    __shared__ __align__(16) char As[32 * 1024];
    __shared__ __align__(16) char Ws[2][16384];
    __shared__ float avg[M_EXP][O_DIM];
    __shared__ float partl[256];
    __shared__ float rho_s[M_EXP], rhohat_s[M_EXP];
    __shared__ float simv[28], prs[28];

    const int t = threadIdx.x;

    if (blockIdx.x == 128) {                       // ---------- loss ----------
        if (blockIdx.y != 0) return;
        const int e = t & 7, grp = t >> 3;         // gpart is [2048][8]
        float sg = 0.f, sc = 0.f;
        for (int b2 = grp * 64; b2 < grp * 64 + 64; ++b2) {
            const float wgt = (b2 < 1024) ? 1.f : 2.f;
            sg += wgt * gpart[b2 * 8 + e];
            sc += wgt * cpart[b2 * 8 + e];
        }
        partl[t] = sg; __syncthreads();
        if (t < 8) { float s = 0.f; for (int g2 = 0; g2 < 32; ++g2) s += partl[t + 8 * g2]; rhohat_s[t] = s; }
        __syncthreads();
        partl[t] = sc; __syncthreads();
        if (t < 8) { float s = 0.f; for (int g2 = 0; g2 < 32; ++g2) s += partl[t + 8 * g2]; rho_s[t] = s; }
        __syncthreads();
        for (int idx = t; idx < M_EXP * O_DIM; idx += 256)
            avg[idx >> 8][idx & 255] = sum_out[idx] / fmaxf(rho_s[idx >> 8], 1.f);
        __syncthreads();
        if (t < 28) {
            int a = 0, p = t;
            while (p >= 7 - a) { p -= 7 - a; ++a; }
            const int b = a + 1 + p;
            float d2 = 0.f;
            for (int o = 0; o < O_DIM; ++o) {
                const float df = avg[a][o] - avg[b][o];
                d2 = fmaf(df, df, d2);
            }
            const bool pr = (rho_s[a] > 0.f) && (rho_s[b] > 0.f);
            simv[t] = pr ? expf(-0.5f * d2) : 0.f;
            prs[t]  = pr ? 1.f : 0.f;
        }
        __syncthreads();
        if (t == 0) {
            float s = 0.f, np = 0.f;
            for (int p = 0; p < 28; ++p) { s += simv[p]; np += prs[p]; }
            out[N_TOK * 2 + 0] = -s / fmaxf(np, 1.f);
            float eq = 0.f;
            for (int m = 0; m < M_EXP; ++m) eq = fmaf(rho_s[m], rhohat_s[m], eq);
            out[N_TOK * 2 + 1] = eq / (float)M_EXP;
        }
        return;
    }

    // ---------- fusion + classifier ----------
    const int w = t >> 6, l = t & 63;
    const int lr = l & 15, lk = l >> 4;
    const int base = blockIdx.x * 32;
    const int half = blockIdx.y;
    const int colbase = half * 256 + w * 64;
    const unsigned short* wfp = WfT + (size_t)half * 256 * 512;

    const int wrl = l >> 2;
    const int wp = l & 3;
    auto stage_w = [&](int kc, int buf) {
#pragma unroll
        for (int s2 = 0; s2 < 4; ++s2) {
            const int row = w * 64 + s2 * 16 + wrl;
            const int lslot = wp ^ ((row >> 1) & 3);
            gload_lds16(wfp + (size_t)row * 512 + kc * 32 + lslot * 8,
                        &Ws[buf][w * 4096 + s2 * 1024]);
        }
    };

    stage_w(0, 0);

    {   // A stage: combined[32][512] = gathered sums of 2 weighted Y rows
        const int r = t >> 3;
        const int c0 = (t & 7) * 64;
        const int n = base + r;
        const int mod = c0 >> 8;
        const int cc = c0 & 255;
        const int i0 = eidx[(mod * N_TOK + n) * 2 + 0];
        const int i1 = eidx[(mod * N_TOK + n) * 2 + 1];
        const int g0 = mod * M_EXP + i0, g1 = mod * M_EXP + i1;
        const int s0 = invslot[g0 * N_TOK + n];
        const int s1 = invslot[g1 * N_TOK + n];
        const unsigned short* y0 = Ybuf + ((size_t)g0 * N_TOK + s0) * 256 + cc;
        const unsigned short* y1 = Ybuf + ((size_t)g1 * N_TOK + s1) * 256 + cc;
#pragma unroll
        for (int q = 0; q < 8; ++q) {
            const bf16x8 a0 = *(const bf16x8*)(y0 + q * 8);
            const bf16x8 a1 = *(const bf16x8*)(y1 + q * 8);
            bf16x8 p;
#pragma unroll
            for (int j = 0; j < 8; ++j)
                p[j] = (short)f2bf(b2f((unsigned short)a0[j]) + b2f((unsigned short)a1[j]));
            *(bf16x8*)&As[swAs(r, (t & 7) * 8 + q)] = p;
        }
    }
    LGKMCNT0;

    f32x4 acc[2][4];
#pragma unroll
    for (int mi = 0; mi < 2; ++mi)
#pragma unroll
        for (int nj = 0; nj < 4; ++nj) { f32x4 z = {0.f,0.f,0.f,0.f}; acc[mi][nj] = z; }

    int cur = 0;
#pragma unroll
    for (int kc = 0; kc < 16; ++kc) {
        const int nb = cur ^ 1;
        if (kc < 15) { stage_w(kc + 1, nb); VMCNT(4); }
        else         { VMCNT(0); }
        BARRIER();
        bf16x8 a[2], b[4];
#pragma unroll
        for (int mi = 0; mi < 2; ++mi)
            a[mi] = *(const bf16x8*)&As[swAs(mi * 16 + lr, kc * 4 + lk)];
#pragma unroll
        for (int nj = 0; nj < 4; ++nj)
            b[nj] = *(const bf16x8*)&Ws[cur][sw64(w * 64 + nj * 16 + lr, lk)];
#pragma unroll
        for (int mi = 0; mi < 2; ++mi)
#pragma unroll
            for (int nj = 0; nj < 4; ++nj)
                acc[mi][nj] = __builtin_amdgcn_mfma_f32_16x16x32_bf16(a[mi], b[nj], acc[mi][nj], 0, 0, 0);
        BARRIER();
        cur = nb;
    }

#pragma unroll
    for (int mi = 0; mi < 2; ++mi)
#pragma unroll
        for (int j = 0; j < 4; ++j) {
            float p0 = 0.f, p1 = 0.f;
#pragma unroll
            for (int nj = 0; nj < 4; ++nj) {
                const int col = colbase + nj * 16 + lr;
                const float r = fmaxf(acc[mi][nj][j] + bf[col], 0.f);
                p0 = fmaf(r, Wc[col * 2 + 0], p0);
                p1 = fmaf(r, Wc[col * 2 + 1], p1);
            }
#pragma unroll
            for (int off = 1; off < 16; off <<= 1) {
                p0 += __shfl_xor(p0, off, 64);
                p1 += __shfl_xor(p1, off, 64);
            }
            if (lr == 0) {
                const int row = base + mi * 16 + lk * 4 + j;
                atomicAdd(&out[row * 2 + 0], p0);
                atomicAdd(&out[row * 2 + 1], p1);
            }
        }
}

// ---------------------------------------------------------------------------
extern "C" void kernel_launch(void* const* d_in, const int* in_sizes, int n_in,
                              void* d_out, int out_size, void* d_ws, size_t ws_size,
                              hipStream_t stream)
{
    const float* Xb = (const float*)d_in[0];
    const float* Xc = (const float*)d_in[1];
    // d_in[2] (vec_fcg) intentionally unused: reference source bug reuses cfg.
    const float* Wg = (const float*)d_in[3];
    const float* bg = (const float*)d_in[4];
    const float* W1 = (const float*)d_in[5];
    const float* b1 = (const float*)d_in[6];
    const float* W2 = (const float*)d_in[7];
    const float* b2 = (const float*)d_in[8];
    const float* Wf = (const float*)d_in[9];
    const float* bf = (const float*)d_in[10];
    const float* Wc = (const float*)d_in[11];
    const float* bc = (const float*)d_in[12];
    float* out = (float*)d_out;

    float* ws = (float*)d_ws;
    float* gpart   = ws;                            // [2048][8]
    float* cpart   = gpart + 2048 * M_EXP;          // [2048][8]
    float* sum_out = cpart + 2048 * M_EXP;          // [8][256]
    float* cfd     = sum_out + M_EXP * O_DIM;       // [16][4096]
    int*   cnti    = (int*)(cfd + NGRP * N_TOK);    // [16]
    int*   list    = cnti + 16;                     // [16][4096]
    float* cwgt    = (float*)(list + NGRP * N_TOK); // [16][4096]
    int*   invslot = (int*)(cwgt + NGRP * N_TOK);   // [16][4096]
    int*   eidx    = invslot + NGRP * N_TOK;        // [2][4096][2]
    unsigned short* W1T = (unsigned short*)(eidx + 2 * N_TOK * 2); // [8][256][512]
    unsigned short* W2T = W1T + (size_t)M_EXP * H_DIM * D_IN;      // [8][256][256]
    unsigned short* WfT = W2T + (size_t)M_EXP * O_DIM * H_DIM;     // [512][512]
    unsigned short* Xbf = WfT + (size_t)F_DIM * 512;               // [2][4096][512]
    unsigned short* Ybuf = Xbf + (size_t)2 * N_TOK * D_IN;         // [16][4096][256]

    prep_gate_kernel<<<dim3(3873), 256, 0, stream>>>(
        Xb, Xc, Wg, bg, W1, W2, Wf, bc,
        W1T, W2T, WfT, Xbf,
        cfd, eidx, gpart, cpart, sum_out, out);

    compact_kernel<<<dim3(NGRP), 256, 0, stream>>>(cfd, cnti, list, cwgt, invslot);

    hy_gemm_kernel<<<dim3(2048), 256, 0, stream>>>(
        Xbf, W1T, W2T, b1, b2, cnti, list, cwgt, Ybuf, sum_out);

    fuse_cls_loss_kernel<<<dim3(129, 2), 256, 0, stream>>>(
        Ybuf, eidx, invslot, WfT, bf, Wc, gpart, cpart, sum_out, out);
}

// Round 16
// 64.265 us; speedup vs baseline: 1.2080x; 1.0039x over previous
//
#include <hip/hip_runtime.h>
#include <hip/hip_bf16.h>

// Problem constants: N=4096, D=512, H=256, O=256, M=8, K=2, F=512, C=2
#define N_TOK 4096
#define D_IN  512
#define H_DIM 256
#define O_DIM 256
#define M_EXP 8
#define F_DIM 512
#define NGRP  16          // 2 modalities x 8 experts

typedef __attribute__((ext_vector_type(8))) short bf16x8;   // 8 bf16 = 4 VGPRs
typedef __attribute__((ext_vector_type(4))) float f32x4;    // MFMA C/D frag

#define VMCNT(n)  asm volatile("s_waitcnt vmcnt(" #n ")" ::: "memory")
#define LGKMCNT0  asm volatile("s_waitcnt lgkmcnt(0)" ::: "memory")
#define BARRIER() __builtin_amdgcn_s_barrier()

// RNE f32 -> bf16 bits
__device__ __forceinline__ unsigned short f2bf(float f) {
    unsigned int u = __float_as_uint(f);
    u = (u + 0x7FFFu + ((u >> 16) & 1u)) >> 16;
    return (unsigned short)u;
}
__device__ __forceinline__ float b2f(unsigned short u) {
    return __uint_as_float((unsigned int)u << 16);
}

// async global->LDS, 16B per lane; LDS dest wave-uniform base + lane*16
__device__ __forceinline__ void gload_lds16(const void* g, void* l) {
    __builtin_amdgcn_global_load_lds(
        (const __attribute__((address_space(1))) unsigned int*)g,
        (__attribute__((address_space(3))) unsigned int*)l, 16, 0, 0);
}

// Swizzled LDS byte offset for [R][32 bf16] tiles (64B rows, 4x16B slots).
__device__ __forceinline__ int sw64(int row, int lslot) {
    return row * 64 + ((lslot ^ ((row >> 1) & 3)) << 4);
}
// 512B rows (32x16B slots): slot ^= row&7.
__device__ __forceinline__ int swHs(int row, int lslot) {
    return row * 512 + ((lslot ^ (row & 7)) << 4);
}
// 1024B rows (64x16B slots): slot ^= row&7.
__device__ __forceinline__ int swAs(int row, int lslot) {
    return row * 1024 + ((lslot ^ (row & 7)) << 4);
}

// ---------------------------------------------------------------------------
// Kernel 1 (merged): weight transposes + WfT fold + out init + sum_out zero +
// gating. Gating writes dense cfd[16][4096], eidx, Xbf, and soft-gate
// partials gpart. Hard counts come exactly from compact's cnti (removed the
// redundant s_c/cpart path).
// ---------------------------------------------------------------------------
__global__ __launch_bounds__(256) void prep_gate_kernel(
    const float* __restrict__ Xb, const float* __restrict__ Xc,
    const float* __restrict__ Wg, const float* __restrict__ bg,
    const float* __restrict__ W1, const float* __restrict__ W2,
    const float* __restrict__ Wf, const float* __restrict__ bc,
    unsigned short* __restrict__ W1T, unsigned short* __restrict__ W2T,
    unsigned short* __restrict__ WfT, unsigned short* __restrict__ Xbf,
    float* __restrict__ cfd, int* __restrict__ eidx,
    float* __restrict__ gpart,
    float* __restrict__ sum_out, float* __restrict__ out)
{
    __shared__ float tile[32][33];
    __shared__ float s_g[M_EXP];
    const int bx = blockIdx.x;
    const int tr = threadIdx.x >> 3, q = threadIdx.x & 7;

    if (bx < 1024) {            // W1 [8][512][256] -> W1T [8][256][512]
        const int e = bx >> 7, tidx = bx & 127;
        const int r0 = (tidx >> 3) * 32, c0 = (tidx & 7) * 32;
        const float* s = W1 + (size_t)e * 512 * 256;
        unsigned short* d = W1T + (size_t)e * 512 * 256;
        *(float4*)&tile[tr][q * 4] = *(const float4*)&s[(size_t)(r0 + tr) * 256 + c0 + q * 4];
        __syncthreads();
        ushort4 o;
        o.x = f2bf(tile[q*4+0][tr]); o.y = f2bf(tile[q*4+1][tr]);
        o.z = f2bf(tile[q*4+2][tr]); o.w = f2bf(tile[q*4+3][tr]);
        *(ushort4*)&d[(size_t)(c0 + tr) * 512 + r0 + q * 4] = o;
    } else if (bx < 1536) {     // W2 [8][256][256] -> W2T [8][256][256]
        const int idx = bx - 1024;
        const int e = idx >> 6, tidx = idx & 63;
        const int r0 = (tidx >> 3) * 32, c0 = (tidx & 7) * 32;
        const float* s = W2 + (size_t)e * 256 * 256;
        unsigned short* d = W2T + (size_t)e * 256 * 256;
        *(float4*)&tile[tr][q * 4] = *(const float4*)&s[(size_t)(r0 + tr) * 256 + c0 + q * 4];
        __syncthreads();
        ushort4 o;
        o.x = f2bf(tile[q*4+0][tr]); o.y = f2bf(tile[q*4+1][tr]);
        o.z = f2bf(tile[q*4+2][tr]); o.w = f2bf(tile[q*4+3][tr]);
        *(ushort4*)&d[(size_t)(c0 + tr) * 256 + r0 + q * 4] = o;
    } else if (bx < 1792) {     // WfT_eff[f][j] = Wf[j][f] + (j>=256 ? Wf[j+256][f] : 0)
        const int idx = bx - 1536;
        const int j0 = (idx >> 4) * 32, f0 = (idx & 15) * 32;
        float4 v = *(const float4*)&Wf[(size_t)(j0 + tr) * F_DIM + f0 + q * 4];
        if (j0 >= 256) {
            const float4 v2 = *(const float4*)&Wf[(size_t)(j0 + tr + 256) * F_DIM + f0 + q * 4];
            v.x += v2.x; v.y += v2.y; v.z += v2.z; v.w += v2.w;
        }
        *(float4*)&tile[tr][q * 4] = v;
        __syncthreads();
        ushort4 o;
        o.x = f2bf(tile[q*4+0][tr]); o.y = f2bf(tile[q*4+1][tr]);
        o.z = f2bf(tile[q*4+2][tr]); o.w = f2bf(tile[q*4+3][tr]);
        *(ushort4*)&WfT[(size_t)(f0 + tr) * 512 + j0 + q * 4] = o;
    } else if (bx < 1824) {     // out init
        const int i = (bx - 1792) * 256 + threadIdx.x;
        out[i] = bc[i & 1];
    } else if (bx < 1825) {     // zero sum_out
#pragma unroll
        for (int k = 0; k < 8; ++k) sum_out[threadIdx.x * 8 + k] = 0.f;
    } else {                    // ---------------- gating ----------------
        const int idx = bx - 1825;
        const int mod = idx >> 10;
        const int b = idx & 1023;
        const float* X = mod ? Xc : Xb;
        const int wave = threadIdx.x >> 6;
        const int lane = threadIdx.x & 63;
        const int n = b * 4 + wave;

        if (threadIdx.x < M_EXP) s_g[threadIdx.x] = 0.f;
        __syncthreads();

        float acc[M_EXP] = {0.f,0.f,0.f,0.f,0.f,0.f,0.f,0.f};
        const float* xrow = X + (size_t)n * D_IN;
        unsigned short* xb = Xbf + (size_t)mod * N_TOK * D_IN + (size_t)n * D_IN;
#pragma unroll
        for (int k = 0; k < 8; ++k) {
            const int d = lane + 64 * k;
            const float xv = xrow[d];
            xb[d] = f2bf(xv);
            const float* wr = Wg + d * M_EXP;
#pragma unroll
            for (int m = 0; m < M_EXP; ++m) acc[m] += xv * wr[m];
        }
#pragma unroll
        for (int off = 1; off < 64; off <<= 1) {
#pragma unroll
            for (int m = 0; m < M_EXP; ++m) acc[m] += __shfl_xor(acc[m], off, 64);
        }
        float g[M_EXP];
        float mx = -1e30f;
#pragma unroll
        for (int m = 0; m < M_EXP; ++m) { g[m] = acc[m] + bg[m]; mx = fmaxf(mx, g[m]); }
        float es = 0.f;
#pragma unroll
        for (int m = 0; m < M_EXP; ++m) { g[m] = expf(g[m] - mx); es += g[m]; }
        const float inv = 1.f / es;
#pragma unroll
        for (int m = 0; m < M_EXP; ++m) g[m] *= inv;

        int i0 = 0; float v0 = g[0];
#pragma unroll
        for (int m = 1; m < M_EXP; ++m) if (g[m] > v0) { v0 = g[m]; i0 = m; }
        int i1 = -1; float v1 = -1e30f;
#pragma unroll
        for (int m = 0; m < M_EXP; ++m) if (m != i0 && g[m] > v1) { v1 = g[m]; i1 = m; }

        if (lane == 0) {
            const float wn = 1.f / (v0 + v1);
#pragma unroll
            for (int m = 0; m < M_EXP; ++m) {
                const float cv = (m == i0) ? v0 * wn : (m == i1) ? v1 * wn : 0.f;
                cfd[(size_t)(mod * M_EXP + m) * N_TOK + n] = cv;
            }
            eidx[(mod * N_TOK + n) * 2 + 0] = i0;
            eidx[(mod * N_TOK + n) * 2 + 1] = i1;
#pragma unroll
            for (int m = 0; m < M_EXP; ++m) atomicAdd(&s_g[m], g[m]);
        }
        __syncthreads();
        if (threadIdx.x < M_EXP)
            gpart[idx * M_EXP + threadIdx.x] = s_g[threadIdx.x];
    }
}

// ---------------------------------------------------------------------------
// Compaction: one block per group. Prefix-sum over cfd[g][*] -> token-ordered
// list/cwgt, inverse map invslot[g][n], exact count cnti[g] (== hard rho),
// pad to 32 multiple.
// ---------------------------------------------------------------------------
__global__ __launch_bounds__(256) void compact_kernel(
    const float* __restrict__ cfd, int* __restrict__ cnti,
    int* __restrict__ list, float* __restrict__ cwgt, int* __restrict__ invslot)
{
    __shared__ int scnt[256];
    const int g = blockIdx.x;
    const int t = threadIdx.x;
    float v[16];
    int cnt = 0;
#pragma unroll
    for (int k = 0; k < 16; ++k) {
        v[k] = cfd[(size_t)g * N_TOK + t * 16 + k];
        cnt += (v[k] > 0.f) ? 1 : 0;
    }
    scnt[t] = cnt;
    __syncthreads();
    for (int off = 1; off < 256; off <<= 1) {
        const int y = (t >= off) ? scnt[t - off] : 0;
        __syncthreads();
        scnt[t] += y;
        __syncthreads();
    }
    const int total = scnt[255];
    int pos = scnt[t] - cnt;                 // exclusive prefix
#pragma unroll
    for (int k = 0; k < 16; ++k) {
        if (v[k] > 0.f) {
            const int n = t * 16 + k;
            list[g * N_TOK + pos] = n;
            cwgt[g * N_TOK + pos] = v[k];
            invslot[g * N_TOK + n] = pos;
            ++pos;
        }
    }
    const int padded = (total + 31) & ~31;
    for (int i = total + t; i < padded; i += 256) {
        list[g * N_TOK + i] = 0;
        cwgt[g * N_TOK + i] = 0.f;
    }
    if (t == 0) cnti[g] = total;
}

// ---------------------------------------------------------------------------
// Fused gathered expert kernel (round-12 version, verified optimum).
// ---------------------------------------------------------------------------
__global__ __launch_bounds__(256, 4) void hy_gemm_kernel(
    const unsigned short* __restrict__ Xbf,    // [2][4096][512] bf16
    const unsigned short* __restrict__ W1T,    // [8][256][512] bf16
    const unsigned short* __restrict__ W2T,    // [8][256][256] bf16
    const float* __restrict__ b1, const float* __restrict__ b2,
    const int* __restrict__ cnti, const int* __restrict__ list,
    const float* __restrict__ cwgt,
    unsigned short* __restrict__ Ybuf,         // [16][4096][256] bf16 (weighted)
    float* __restrict__ sum_out)
{
    __shared__ __align__(16) char lds[36864];

    const int bid = blockIdx.x;
    const int xcd = bid & 7, r = bid >> 3;
    const int g  = xcd * 2 + (r & 1);
    const int rt = r >> 1;
    const int cnt = cnti[g];
    if (rt * 32 >= cnt) return;
    const int e = g & 7, mod = g >> 3;
    const int r0 = rt * 32;

    const int t = threadIdx.x;
    const int w = t >> 6, l = t & 63;
    const int lr = l & 15, lk = l >> 4;
    const int wcol = w * 64;

    const unsigned short* w1p = W1T + (size_t)e * H_DIM * D_IN;
    const unsigned short* w2p = W2T + (size_t)e * O_DIM * H_DIM;

    float bv1[4], bv2[4];
#pragma unroll
    for (int nj = 0; nj < 4; ++nj) {
        bv1[nj] = b1[e * 256 + wcol + nj * 16 + lr];
        bv2[nj] = b2[e * 256 + wcol + nj * 16 + lr];
    }

    const unsigned short* aptr = nullptr;
    if (w < 2) {
        const int arow = w * 16 + (l >> 2);
        const int ls = (l & 3) ^ ((arow >> 1) & 3);
        const int n = list[g * N_TOK + r0 + arow];
        aptr = Xbf + (size_t)mod * N_TOK * D_IN + (size_t)n * 512 + ls * 8;
    }
    const int brl = l >> 2;
    const int bp = l & 3;

    f32x4 acc[2][4];
#pragma unroll
    for (int mi = 0; mi < 2; ++mi)
#pragma unroll
        for (int nj = 0; nj < 4; ++nj) { f32x4 z = {0.f,0.f,0.f,0.f}; acc[mi][nj] = z; }

    for (int kc = 0; kc < 16; ++kc) {
        if (w < 2) gload_lds16(aptr + kc * 32, lds + w * 1024);
#pragma unroll
        for (int s = 0; s < 4; ++s) {
            const int row = w * 64 + s * 16 + brl;
            const int ls = bp ^ ((row >> 1) & 3);
            gload_lds16(w1p + (size_t)row * 512 + kc * 32 + ls * 8,
                        lds + 2048 + w * 4096 + s * 1024);
        }
        __syncthreads();
        bf16x8 a[2], b[4];
#pragma unroll
        for (int mi = 0; mi < 2; ++mi)
            a[mi] = *(const bf16x8*)(lds + sw64(mi * 16 + lr, lk));
#pragma unroll
        for (int nj = 0; nj < 4; ++nj)
            b[nj] = *(const bf16x8*)(lds + 2048 + sw64(wcol + nj * 16 + lr, lk));
#pragma unroll
        for (int mi = 0; mi < 2; ++mi)
#pragma unroll
            for (int nj = 0; nj < 4; ++nj)
                acc[mi][nj] = __builtin_amdgcn_mfma_f32_16x16x32_bf16(a[mi], b[nj], acc[mi][nj], 0, 0, 0);
        __syncthreads();
    }

#pragma unroll
    for (int mi = 0; mi < 2; ++mi)
#pragma unroll
        for (int nj = 0; nj < 4; ++nj) {
            const int col = wcol + nj * 16 + lr;
            const int cslot = col >> 3;
            const int cbyte = (col & 7) * 2;
#pragma unroll
            for (int j = 0; j < 4; ++j) {
                const int row = mi * 16 + lk * 4 + j;
                *(unsigned short*)(lds + 18432 + row * 512 + ((cslot ^ (row & 7)) << 4) + cbyte) =
                    f2bf(fmaxf(acc[mi][nj][j] + bv1[nj], 0.f));
            }
        }
#pragma unroll
    for (int mi = 0; mi < 2; ++mi)
#pragma unroll
        for (int nj = 0; nj < 4; ++nj) { f32x4 z = {0.f,0.f,0.f,0.f}; acc[mi][nj] = z; }

    for (int kc = 0; kc < 8; ++kc) {
#pragma unroll
        for (int s = 0; s < 4; ++s) {
            const int row = w * 64 + s * 16 + brl;
            const int ls = bp ^ ((row >> 1) & 3);
            gload_lds16(w2p + (size_t)row * 256 + kc * 32 + ls * 8,
                        lds + 2048 + w * 4096 + s * 1024);
        }
        __syncthreads();
        bf16x8 a[2], b[4];
#pragma unroll
        for (int mi = 0; mi < 2; ++mi)
            a[mi] = *(const bf16x8*)(lds + 18432 + swHs(mi * 16 + lr, kc * 4 + lk));
#pragma unroll
        for (int nj = 0; nj < 4; ++nj)
            b[nj] = *(const bf16x8*)(lds + 2048 + sw64(wcol + nj * 16 + lr, lk));
#pragma unroll
        for (int mi = 0; mi < 2; ++mi)
#pragma unroll
            for (int nj = 0; nj < 4; ++nj)
                acc[mi][nj] = __builtin_amdgcn_mfma_f32_16x16x32_bf16(a[mi], b[nj], acc[mi][nj], 0, 0, 0);
        __syncthreads();
    }

    float sacc[4] = {0.f, 0.f, 0.f, 0.f};
#pragma unroll
    for (int mi = 0; mi < 2; ++mi)
#pragma unroll
        for (int j2 = 0; j2 < 4; ++j2) {
            const int row = mi * 16 + lk * 4 + j2;
            const float wv = cwgt[g * N_TOK + r0 + row];
            const bool valid = wv > 0.f;
#pragma unroll
            for (int nj = 0; nj < 4; ++nj) {
                const float v = acc[mi][nj][j2] + bv2[nj];
                if (valid) sacc[nj] += v;
                const int col = wcol + nj * 16 + lr;
                *(unsigned short*)(lds + row * 512 + col * 2) = f2bf(wv * v);
            }
        }
    __syncthreads();
#pragma unroll
    for (int q2 = 0; q2 < 4; ++q2) {
        const int u = q2 * 256 + t;
        const int row = u >> 5, cs = u & 31;
        *(bf16x8*)(Ybuf + (((size_t)g * N_TOK + r0 + row) * 256 + cs * 8)) =
            *(const bf16x8*)(lds + u * 16);
    }
#pragma unroll
    for (int nj = 0; nj < 4; ++nj) {
        sacc[nj] += __shfl_xor(sacc[nj], 16, 64);
        sacc[nj] += __shfl_xor(sacc[nj], 32, 64);
    }
    if (lk == 0) {
        const float modw = mod ? 2.f : 1.f;
#pragma unroll
        for (int nj = 0; nj < 4; ++nj)
            atomicAdd(&sum_out[e * O_DIM + wcol + nj * 16 + lr], sacc[nj] * modw);
    }
}

// ---------------------------------------------------------------------------
// Fusion + classifier (x<128) + losses (block x==128,y==0). Round-12 fuse.
// Loss: hard counts rho from cnti (exact integers); soft usage from gpart.
// ---------------------------------------------------------------------------
__global__ __launch_bounds__(256, 2) void fuse_cls_loss_kernel(
    const unsigned short* __restrict__ Ybuf,
    const int* __restrict__ eidx, const int* __restrict__ invslot,
    const unsigned short* __restrict__ WfT, const float* __restrict__ bf,
    const float* __restrict__ Wc,
    const float* __restrict__ gpart, const int* __restrict__ cnti,
    const float* __restrict__ sum_out, float* __restrict__ out)
{
    __shared__ __align__(16) char As[32 * 1024];
    __shared__ __align__(16) char Ws[2][16384];
    __shared__ float avg[M_EXP][O_DIM];
    __shared__ float partl[256];
    __shared__ float rho_s[M_EXP], rhohat_s[M_EXP];
    __shared__ float simv[28], prs[28];

    const int t = threadIdx.x;

    if (blockIdx.x == 128) {                       // ---------- loss ----------
        if (blockIdx.y != 0) return;
        const int e = t & 7, grp = t >> 3;         // gpart is [2048][8]
        float sg = 0.f;
        for (int b2 = grp * 64; b2 < grp * 64 + 64; ++b2) {
            const float wgt = (b2 < 1024) ? 1.f : 2.f;
            sg += wgt * gpart[b2 * 8 + e];
        }
        partl[t] = sg; __syncthreads();
        if (t < 8) { float s = 0.f; for (int g2 = 0; g2 < 32; ++g2) s += partl[t + 8 * g2]; rhohat_s[t] = s; }
        if (t >= 8 && t < 16)                       // exact hard counts from cnti
            rho_s[t - 8] = (float)cnti[t - 8] + 2.f * (float)cnti[M_EXP + t - 8];
        __syncthreads();
        for (int idx = t; idx < M_EXP * O_DIM; idx += 256)
            avg[idx >> 8][idx & 255] = sum_out[idx] / fmaxf(rho_s[idx >> 8], 1.f);
        __syncthreads();
        if (t < 28) {
            int a = 0, p = t;
            while (p >= 7 - a) { p -= 7 - a; ++a; }
            const int b = a + 1 + p;
            float d2 = 0.f;
            for (int o = 0; o < O_DIM; ++o) {
                const float df = avg[a][o] - avg[b][o];
                d2 = fmaf(df, df, d2);
            }
            const bool pr = (rho_s[a] > 0.f) && (rho_s[b] > 0.f);
            simv[t] = pr ? expf(-0.5f * d2) : 0.f;
            prs[t]  = pr ? 1.f : 0.f;
        }
        __syncthreads();
        if (t == 0) {
            float s = 0.f, np = 0.f;
            for (int p = 0; p < 28; ++p) { s += simv[p]; np += prs[p]; }
            out[N_TOK * 2 + 0] = -s / fmaxf(np, 1.f);
            float eq = 0.f;
            for (int m = 0; m < M_EXP; ++m) eq = fmaf(rho_s[m], rhohat_s[m], eq);
            out[N_TOK * 2 + 1] = eq / (float)M_EXP;
        }
        return;
    }

    // ---------- fusion + classifier ----------
    const int w = t >> 6, l = t & 63;
    const int lr = l & 15, lk = l >> 4;
    const int base = blockIdx.x * 32;
    const int half = blockIdx.y;
    const int colbase = half * 256 + w * 64;
    const unsigned short* wfp = WfT + (size_t)half * 256 * 512;

    const int wrl = l >> 2;
    const int wp = l & 3;
    auto stage_w = [&](int kc, int buf) {
#pragma unroll
        for (int s2 = 0; s2 < 4; ++s2) {
            const int row = w * 64 + s2 * 16 + wrl;
            const int lslot = wp ^ ((row >> 1) & 3);
            gload_lds16(wfp + (size_t)row * 512 + kc * 32 + lslot * 8,
                        &Ws[buf][w * 4096 + s2 * 1024]);
        }
    };

    stage_w(0, 0);

    {   // A stage: combined[32][512] = gathered sums of 2 weighted Y rows
        const int r = t >> 3;
        const int c0 = (t & 7) * 64;
        const int n = base + r;
        const int mod = c0 >> 8;
        const int cc = c0 & 255;
        const int i0 = eidx[(mod * N_TOK + n) * 2 + 0];
        const int i1 = eidx[(mod * N_TOK + n) * 2 + 1];
        const int g0 = mod * M_EXP + i0, g1 = mod * M_EXP + i1;
        const int s0 = invslot[g0 * N_TOK + n];
        const int s1 = invslot[g1 * N_TOK + n];
        const unsigned short* y0 = Ybuf + ((size_t)g0 * N_TOK + s0) * 256 + cc;
        const unsigned short* y1 = Ybuf + ((size_t)g1 * N_TOK + s1) * 256 + cc;
#pragma unroll
        for (int q = 0; q < 8; ++q) {
            const bf16x8 a0 = *(const bf16x8*)(y0 + q * 8);
            const bf16x8 a1 = *(const bf16x8*)(y1 + q * 8);
            bf16x8 p;
#pragma unroll
            for (int j = 0; j < 8; ++j)
                p[j] = (short)f2bf(b2f((unsigned short)a0[j]) + b2f((unsigned short)a1[j]));
            *(bf16x8*)&As[swAs(r, (t & 7) * 8 + q)] = p;
        }
    }
    LGKMCNT0;

    f32x4 acc[2][4];
#pragma unroll
    for (int mi = 0; mi < 2; ++mi)
#pragma unroll
        for (int nj = 0; nj < 4; ++nj) { f32x4 z = {0.f,0.f,0.f,0.f}; acc[mi][nj] = z; }

    int cur = 0;
#pragma unroll
    for (int kc = 0; kc < 16; ++kc) {
        const int nb = cur ^ 1;
        if (kc < 15) { stage_w(kc + 1, nb); VMCNT(4); }
        else         { VMCNT(0); }
        BARRIER();
        bf16x8 a[2], b[4];
#pragma unroll
        for (int mi = 0; mi < 2; ++mi)
            a[mi] = *(const bf16x8*)&As[swAs(mi * 16 + lr, kc * 4 + lk)];
#pragma unroll
        for (int nj = 0; nj < 4; ++nj)
            b[nj] = *(const bf16x8*)&Ws[cur][sw64(w * 64 + nj * 16 + lr, lk)];
#pragma unroll
        for (int mi = 0; mi < 2; ++mi)
#pragma unroll
            for (int nj = 0; nj < 4; ++nj)
                acc[mi][nj] = __builtin_amdgcn_mfma_f32_16x16x32_bf16(a[mi], b[nj], acc[mi][nj], 0, 0, 0);
        BARRIER();
        cur = nb;
    }

#pragma unroll
    for (int mi = 0; mi < 2; ++mi)
#pragma unroll
        for (int j = 0; j < 4; ++j) {
            float p0 = 0.f, p1 = 0.f;
#pragma unroll
            for (int nj = 0; nj < 4; ++nj) {
                const int col = colbase + nj * 16 + lr;
                const float r = fmaxf(acc[mi][nj][j] + bf[col], 0.f);
                p0 = fmaf(r, Wc[col * 2 + 0], p0);
                p1 = fmaf(r, Wc[col * 2 + 1], p1);
            }
#pragma unroll
            for (int off = 1; off < 16; off <<= 1) {
                p0 += __shfl_xor(p0, off, 64);
                p1 += __shfl_xor(p1, off, 64);
            }
            if (lr == 0) {
                const int row = base + mi * 16 + lk * 4 + j;
                atomicAdd(&out[row * 2 + 0], p0);
                atomicAdd(&out[row * 2 + 1], p1);
            }
        }
}

// ---------------------------------------------------------------------------
extern "C" void kernel_launch(void* const* d_in, const int* in_sizes, int n_in,
                              void* d_out, int out_size, void* d_ws, size_t ws_size,
                              hipStream_t stream)
{
    const float* Xb = (const float*)d_in[0];
    const float* Xc = (const float*)d_in[1];
    // d_in[2] (vec_fcg) intentionally unused: reference source bug reuses cfg.
    const float* Wg = (const float*)d_in[3];
    const float* bg = (const float*)d_in[4];
    const float* W1 = (const float*)d_in[5];
    const float* b1 = (const float*)d_in[6];
    const float* W2 = (const float*)d_in[7];
    const float* b2 = (const float*)d_in[8];
    const float* Wf = (const float*)d_in[9];
    const float* bf = (const float*)d_in[10];
    const float* Wc = (const float*)d_in[11];
    const float* bc = (const float*)d_in[12];
    float* out = (float*)d_out;

    float* ws = (float*)d_ws;
    float* gpart   = ws;                            // [2048][8]
    float* sum_out = gpart + 2048 * M_EXP;          // [8][256]
    float* cfd     = sum_out + M_EXP * O_DIM;       // [16][4096]
    int*   cnti    = (int*)(cfd + NGRP * N_TOK);    // [16]
    int*   list    = cnti + 16;                     // [16][4096]
    float* cwgt    = (float*)(list + NGRP * N_TOK); // [16][4096]
    int*   invslot = (int*)(cwgt + NGRP * N_TOK);   // [16][4096]
    int*   eidx    = invslot + NGRP * N_TOK;        // [2][4096][2]
    unsigned short* W1T = (unsigned short*)(eidx + 2 * N_TOK * 2); // [8][256][512]
    unsigned short* W2T = W1T + (size_t)M_EXP * H_DIM * D_IN;      // [8][256][256]
    unsigned short* WfT = W2T + (size_t)M_EXP * O_DIM * H_DIM;     // [512][512]
    unsigned short* Xbf = WfT + (size_t)F_DIM * 512;               // [2][4096][512]
    unsigned short* Ybuf = Xbf + (size_t)2 * N_TOK * D_IN;         // [16][4096][256]

    prep_gate_kernel<<<dim3(3873), 256, 0, stream>>>(
        Xb, Xc, Wg, bg, W1, W2, Wf, bc,
        W1T, W2T, WfT, Xbf,
        cfd, eidx, gpart, sum_out, out);

    compact_kernel<<<dim3(NGRP), 256, 0, stream>>>(cfd, cnti, list, cwgt, invslot);

    hy_gemm_kernel<<<dim3(2048), 256, 0, stream>>>(
        Xbf, W1T, W2T, b1, b2, cnti, list, cwgt, Ybuf, sum_out);

    fuse_cls_loss_kernel<<<dim3(129, 2), 256, 0, stream>>>(
        Ybuf, eidx, invslot, WfT, bf, Wc, gpart, cnti, sum_out, out);
}